// Round 1
// baseline (611.856 us; speedup 1.0000x reference)
//
#include <hip/hip_runtime.h>
#include <cstdint>
#include <cstddef>

// ---------------------------------------------------------------------------
// Transformer block on MI355X (gfx950), bf16 MFMA path.
//   x:[2,2048,1024] fp32.  All GEMMs via mfma_f32_16x16x32_bf16 (m97 ladder
//   structure: 128x128 tile, BK=32, global_load_lds width=16).
//   Attention: flash-style, 64 Q-rows/block, K:[T,hd], V transposed [hd,T].
//   Residual stream kept fp32 for accuracy; activations bf16 into MFMA.
// ---------------------------------------------------------------------------

typedef unsigned short u16;
typedef short bf16x8 __attribute__((ext_vector_type(8)));
typedef float f32x4 __attribute__((ext_vector_type(4)));

#define C_EMBD 1024
#define T_SEQ  2048
#define N_BATCH 2
#define N_HEADS 16
#define HEAD_D 64
#define M_TOK  4096   // N_BATCH * T_SEQ

__device__ __forceinline__ u16 f2b(float f) {
  union { float f; unsigned u; } v; v.f = f;
  unsigned r = (v.u + 0x7fffu + ((v.u >> 16) & 1u)) >> 16;  // RNE
  return (u16)r;
}
__device__ __forceinline__ float b2f(u16 u) {
  union { unsigned u; float f; } v; v.u = ((unsigned)u) << 16;
  return v.f;
}
__device__ __forceinline__ void load_lds16(const void* g, void* l) {
  __builtin_amdgcn_global_load_lds(
      (const __attribute__((address_space(1))) void*)g,
      (__attribute__((address_space(3))) void*)l, 16, 0, 0);
}

// ---------------------------------------------------------------------------
// Weight transpose + cast: W[K][N] fp32 -> Wt[N][K] bf16
// ---------------------------------------------------------------------------
__global__ __launch_bounds__(256) void transpose_cast(
    const float* __restrict__ W, u16* __restrict__ Wt, int K, int N) {
  __shared__ float tile[32][33];
  const int n0 = blockIdx.x * 32, k0 = blockIdx.y * 32;
  const int tx = threadIdx.x & 31, ty = threadIdx.x >> 5;  // ty in [0,8)
#pragma unroll
  for (int i = 0; i < 32; i += 8)
    tile[ty + i][tx] = W[(size_t)(k0 + ty + i) * N + n0 + tx];
  __syncthreads();
#pragma unroll
  for (int i = 0; i < 32; i += 8)
    Wt[(size_t)(n0 + ty + i) * K + k0 + tx] = f2b(tile[tx][ty + i]);
}

// ---------------------------------------------------------------------------
// LayerNorm over rows of 1024 fp32 -> bf16 out. One block (256 thr) per row.
// ---------------------------------------------------------------------------
__global__ __launch_bounds__(256) void ln_cast(
    const float* __restrict__ X, const float* __restrict__ g,
    const float* __restrict__ b, u16* __restrict__ Y) {
  const int row = blockIdx.x;
  const int tid = threadIdx.x;
  const float4 v = ((const float4*)(X + (size_t)row * C_EMBD))[tid];
  float s = v.x + v.y + v.z + v.w;
  float ss = v.x * v.x + v.y * v.y + v.z * v.z + v.w * v.w;
#pragma unroll
  for (int off = 32; off > 0; off >>= 1) {
    s += __shfl_down(s, off, 64);
    ss += __shfl_down(ss, off, 64);
  }
  __shared__ float red[8];
  __shared__ float stats[2];
  const int wave = tid >> 6, lane = tid & 63;
  if (lane == 0) { red[wave] = s; red[4 + wave] = ss; }
  __syncthreads();
  if (tid == 0) {
    float S = red[0] + red[1] + red[2] + red[3];
    float SS = red[4] + red[5] + red[6] + red[7];
    float mu = S * (1.0f / C_EMBD);
    float var = SS * (1.0f / C_EMBD) - mu * mu;
    stats[0] = mu;
    stats[1] = rsqrtf(var + 1e-5f);
  }
  __syncthreads();
  const float mu = stats[0], rs = stats[1];
  const float4 gv = ((const float4*)g)[tid];
  const float4 bv = ((const float4*)b)[tid];
  ushort4 o;
  o.x = f2b((v.x - mu) * rs * gv.x + bv.x);
  o.y = f2b((v.y - mu) * rs * gv.y + bv.y);
  o.z = f2b((v.z - mu) * rs * gv.z + bv.z);
  o.w = f2b((v.w - mu) * rs * gv.w + bv.w);
  ((ushort4*)(Y + (size_t)row * C_EMBD))[tid] = o;
}

// ---------------------------------------------------------------------------
// GEMM: C[M,N] = A[M,K](bf16) * Bt[N,K](bf16)^T + bias, m97 structure.
// 256 threads = 4 waves; 128x128 tile; BK=32; each wave does 64x64 (4x4 tiles).
// ---------------------------------------------------------------------------
enum { EPI_BF16 = 0, EPI_RES_F32 = 1, EPI_GELU_BF16 = 2 };

template <int EPI>
__global__ __launch_bounds__(256) void gemm_bt(
    const u16* __restrict__ A, const u16* __restrict__ Bt,
    const float* __restrict__ bias, const float* __restrict__ res,
    void* __restrict__ Cout, int M, int N, int K) {
  __shared__ u16 As[128 * 32];
  __shared__ u16 Bs[128 * 32];
  const int tid = threadIdx.x;
  const int wave = tid >> 6, lane = tid & 63;
  const int quad = lane >> 4, l16 = lane & 15;
  const int m0 = blockIdx.y * 128, n0 = blockIdx.x * 128;
  const int wm = (wave >> 1) * 64, wn = (wave & 1) * 64;

  f32x4 acc[4][4] = {};

  const int kTiles = K >> 5;
  for (int kt = 0; kt < kTiles; ++kt) {
    const int k0 = kt << 5;
    // stage 128x32 A-tile and B-tile: 512 16B chunks each, 2 per thread each.
    // chunk c -> row c>>2, 16B-col c&3; LDS dest lane-linear (wave-uniform+lane*16).
#pragma unroll
    for (int i = 0; i < 2; ++i) {
      const int c = tid + i * 256;
      const int row = c >> 2, cc = (c & 3) * 8;
      load_lds16(A + (size_t)(m0 + row) * K + k0 + cc, &As[c * 8]);
      load_lds16(Bt + (size_t)(n0 + row) * K + k0 + cc, &Bs[c * 8]);
    }
    __syncthreads();
    bf16x8 aF[4], bF[4];
#pragma unroll
    for (int t = 0; t < 4; ++t) {
      aF[t] = *(const bf16x8*)&As[(wm + t * 16 + l16) * 32 + quad * 8];
      bF[t] = *(const bf16x8*)&Bs[(wn + t * 16 + l16) * 32 + quad * 8];
    }
#pragma unroll
    for (int tm = 0; tm < 4; ++tm)
#pragma unroll
      for (int tn = 0; tn < 4; ++tn)
        acc[tm][tn] = __builtin_amdgcn_mfma_f32_16x16x32_bf16(
            aF[tm], bF[tn], acc[tm][tn], 0, 0, 0);
    __syncthreads();
  }

  // epilogue: C/D layout col=lane&15, row=quad*4+reg
#pragma unroll
  for (int tm = 0; tm < 4; ++tm) {
#pragma unroll
    for (int r = 0; r < 4; ++r) {
      const int row = m0 + wm + tm * 16 + quad * 4 + r;
#pragma unroll
      for (int tn = 0; tn < 4; ++tn) {
        const int col = n0 + wn + tn * 16 + l16;
        float v = acc[tm][tn][r] + bias[col];
        if constexpr (EPI == EPI_RES_F32) {
          v += res[(size_t)row * N + col];
          ((float*)Cout)[(size_t)row * N + col] = v;
        } else if constexpr (EPI == EPI_GELU_BF16) {
          v = 0.5f * v * (1.0f + erff(v * 0.70710678118f));
          ((u16*)Cout)[(size_t)row * N + col] = f2b(v);
        } else {
          ((u16*)Cout)[(size_t)row * N + col] = f2b(v);
        }
      }
    }
  }
}

// ---------------------------------------------------------------------------
// Reorder qkv[M,3C] bf16 -> Q[BH,T,hd] (scaled 1/8), K[BH,T,hd], Vt[BH,hd,T]
// Block: one (bh, 64-token tile). 256 threads.
// ---------------------------------------------------------------------------
__global__ __launch_bounds__(256) void reorder_qkv(
    const u16* __restrict__ qkv, u16* __restrict__ Q, u16* __restrict__ Kb,
    u16* __restrict__ Vt) {
  const int bh = blockIdx.y, tb = blockIdx.x;
  const int b = bh >> 4, h = bh & 15;
  const size_t row0 = (size_t)b * T_SEQ + tb * 64;  // qkv row base
  __shared__ u16 vt[64][68];
  const int tid = threadIdx.x;
#pragma unroll
  for (int i = 0; i < 4; ++i) {
    const int e = tid + i * 256;
    const int row = e >> 4, c4 = (e & 15) * 4;
    const u16* src = qkv + (row0 + row) * (3 * C_EMBD) + h * HEAD_D;
    // Q with 1/sqrt(hd) pre-scale
    ushort4 qv = *(const ushort4*)(src + c4);
    ushort4 qo;
    qo.x = f2b(b2f(qv.x) * 0.125f);
    qo.y = f2b(b2f(qv.y) * 0.125f);
    qo.z = f2b(b2f(qv.z) * 0.125f);
    qo.w = f2b(b2f(qv.w) * 0.125f);
    const size_t dst = ((size_t)bh * T_SEQ + tb * 64 + row) * HEAD_D + c4;
    *(ushort4*)(Q + dst) = qo;
    *(ushort4*)(Kb + dst) = *(const ushort4*)(src + C_EMBD + c4);
    ushort4 vv = *(const ushort4*)(src + 2 * C_EMBD + c4);
    vt[row][c4] = vv.x; vt[row][c4 + 1] = vv.y;
    vt[row][c4 + 2] = vv.z; vt[row][c4 + 3] = vv.w;
  }
  __syncthreads();
#pragma unroll
  for (int i = 0; i < 4; ++i) {
    const int e = tid + i * 256;
    const int d = e >> 4, t4 = (e & 15) * 4;
    ushort4 ov;
    ov.x = vt[t4][d]; ov.y = vt[t4 + 1][d];
    ov.z = vt[t4 + 2][d]; ov.w = vt[t4 + 3][d];
    *(ushort4*)(Vt + ((size_t)bh * HEAD_D + d) * T_SEQ + tb * 64 + t4) = ov;
  }
}

// ---------------------------------------------------------------------------
// Flash attention (causal). Grid: x = qtile (T/64), y = bh. 256 thr = 4 waves.
// Wave w owns Q rows [q0+16w, q0+16w+16). Iterates 64-key tiles to diagonal.
// Y written as bf16 [B,T,C] (head-interleaved) to feed proj GEMM.
// ---------------------------------------------------------------------------
__global__ __launch_bounds__(256) void attn_fwd(
    const u16* __restrict__ Q, const u16* __restrict__ Kb,
    const u16* __restrict__ Vt, u16* __restrict__ Y) {
  const int bh = blockIdx.y, qb = blockIdx.x;
  const int tid = threadIdx.x;
  const int wave = tid >> 6, lane = tid & 63;
  const int quad = lane >> 4, l16 = lane & 15;
  const int q0 = qb * 64;
  const u16* Qp = Q + (size_t)bh * T_SEQ * HEAD_D;
  const u16* Kp = Kb + (size_t)bh * T_SEQ * HEAD_D;
  const u16* Vp = Vt + (size_t)bh * HEAD_D * T_SEQ;

  // Q A-frags (row = q0 + wave*16 + l16), kept across all K-tiles
  const int qrow = q0 + wave * 16 + l16;
  bf16x8 qF[2];
  qF[0] = *(const bf16x8*)&Qp[(size_t)qrow * HEAD_D + quad * 8];
  qF[1] = *(const bf16x8*)&Qp[(size_t)qrow * HEAD_D + 32 + quad * 8];

  f32x4 o[4] = {};
  float mrun[4], lrun[4];
#pragma unroll
  for (int r = 0; r < 4; ++r) { mrun[r] = -3e38f; lrun[r] = 0.0f; }

  __shared__ u16 Pl[4][16 * 64];

  for (int kb = 0; kb <= qb; ++kb) {
    const int k0 = kb * 64;
    f32x4 s[4] = {};
#pragma unroll
    for (int ks = 0; ks < 2; ++ks) {
#pragma unroll
      for (int nt = 0; nt < 4; ++nt) {
        bf16x8 kF = *(const bf16x8*)
            &Kp[(size_t)(k0 + nt * 16 + l16) * HEAD_D + ks * 32 + quad * 8];
        s[nt] = __builtin_amdgcn_mfma_f32_16x16x32_bf16(qF[ks], kF, s[nt],
                                                        0, 0, 0);
      }
    }
    if (kb == qb) {  // only the diagonal tile needs masking
#pragma unroll
      for (int nt = 0; nt < 4; ++nt) {
        const int key = k0 + nt * 16 + l16;
#pragma unroll
        for (int r = 0; r < 4; ++r) {
          const int qq = q0 + wave * 16 + quad * 4 + r;
          if (key > qq) s[nt][r] = -3e38f;
        }
      }
    }
    // online softmax per row (rows live in quads; reduce over 16 lanes)
#pragma unroll
    for (int r = 0; r < 4; ++r) {
      float m = fmaxf(fmaxf(s[0][r], s[1][r]), fmaxf(s[2][r], s[3][r]));
#pragma unroll
      for (int off = 1; off < 16; off <<= 1)
        m = fmaxf(m, __shfl_xor(m, off, 64));
      const float nm = fmaxf(mrun[r], m);
      const float alpha = __expf(mrun[r] - nm);
      mrun[r] = nm;
      float sum = 0.0f;
#pragma unroll
      for (int nt = 0; nt < 4; ++nt) {
        const float p = __expf(s[nt][r] - nm);
        s[nt][r] = p;
        sum += p;
      }
#pragma unroll
      for (int off = 1; off < 16; off <<= 1)
        sum += __shfl_xor(sum, off, 64);
      lrun[r] = lrun[r] * alpha + sum;
#pragma unroll
      for (int nt = 0; nt < 4; ++nt) o[nt][r] *= alpha;
    }
    // P: C-layout -> LDS -> A-layout (per-wave private tile)
#pragma unroll
    for (int nt = 0; nt < 4; ++nt)
#pragma unroll
      for (int r = 0; r < 4; ++r)
        Pl[wave][(quad * 4 + r) * 64 + nt * 16 + l16] = f2b(s[nt][r]);
    __syncthreads();
#pragma unroll
    for (int ks = 0; ks < 2; ++ks) {
      bf16x8 aP = *(const bf16x8*)&Pl[wave][l16 * 64 + ks * 32 + quad * 8];
#pragma unroll
      for (int nt = 0; nt < 4; ++nt) {
        bf16x8 vF = *(const bf16x8*)
            &Vp[(size_t)(nt * 16 + l16) * T_SEQ + k0 + ks * 32 + quad * 8];
        o[nt] = __builtin_amdgcn_mfma_f32_16x16x32_bf16(aP, vF, o[nt], 0, 0, 0);
      }
    }
    __syncthreads();
  }

  // write O / l -> Y bf16 [B,T,C]
  const int b = bh >> 4, h = bh & 15;
  u16* yp = Y + ((size_t)(b * T_SEQ + q0 + wave * 16)) * C_EMBD + h * HEAD_D;
#pragma unroll
  for (int nt = 0; nt < 4; ++nt)
#pragma unroll
    for (int r = 0; r < 4; ++r)
      yp[(size_t)(quad * 4 + r) * C_EMBD + nt * 16 + l16] =
          f2b(o[nt][r] / lrun[r]);
}

// ---------------------------------------------------------------------------
// Host side
// ---------------------------------------------------------------------------
extern "C" void kernel_launch(void* const* d_in, const int* in_sizes, int n_in,
                              void* d_out, int out_size, void* d_ws,
                              size_t ws_size, hipStream_t stream) {
  const float* x      = (const float*)d_in[0];
  const float* W_attn = (const float*)d_in[1];
  const float* b_attn = (const float*)d_in[2];
  const float* W_proj = (const float*)d_in[3];
  const float* b_proj = (const float*)d_in[4];
  const float* W_fc   = (const float*)d_in[5];
  const float* b_fc   = (const float*)d_in[6];
  const float* W_fc2  = (const float*)d_in[7];
  const float* b_fc2  = (const float*)d_in[8];
  const float* ln1_g  = (const float*)d_in[9];
  const float* ln1_b  = (const float*)d_in[10];
  const float* ln2_g  = (const float*)d_in[11];
  const float* ln2_b  = (const float*)d_in[12];

  // workspace layout (bytes): ~109 MB total
  u16* wqkvT = (u16*)d_ws;                            // [3072][1024] bf16
  u16* wprojT = wqkvT + (size_t)3072 * 1024;          // [1024][1024]
  u16* wfcT  = wprojT + (size_t)1024 * 1024;          // [4096][1024]
  u16* wfc2T = wfcT + (size_t)4096 * 1024;            // [1024][4096]
  u16* Abuf  = wfc2T + (size_t)1024 * 4096;           // [4096][1024] bf16 (ln out / attn y)
  float* x1  = (float*)(Abuf + (size_t)M_TOK * C_EMBD);  // [4096][1024] f32
  u16* hbuf  = (u16*)(x1 + (size_t)M_TOK * C_EMBD);   // [4096][4096] bf16 (also qkv)
  u16* qkvb  = hbuf;                                  // [4096][3072] bf16 (dead before h)
  u16* Qb    = hbuf + (size_t)M_TOK * 4096;           // [32][2048][64]
  u16* Kbuf  = Qb + (size_t)32 * T_SEQ * HEAD_D;
  u16* Vtb   = Kbuf + (size_t)32 * T_SEQ * HEAD_D;

  const dim3 blk(256);

  // 1. weights -> bf16 transposed
  transpose_cast<<<dim3(3072 / 32, 1024 / 32), blk, 0, stream>>>(W_attn, wqkvT, 1024, 3072);
  transpose_cast<<<dim3(1024 / 32, 1024 / 32), blk, 0, stream>>>(W_proj, wprojT, 1024, 1024);
  transpose_cast<<<dim3(4096 / 32, 1024 / 32), blk, 0, stream>>>(W_fc, wfcT, 1024, 4096);
  transpose_cast<<<dim3(1024 / 32, 4096 / 32), blk, 0, stream>>>(W_fc2, wfc2T, 4096, 1024);

  // 2. ln1 -> bf16
  ln_cast<<<M_TOK, blk, 0, stream>>>(x, ln1_g, ln1_b, Abuf);

  // 3. qkv = ln1 @ W_attn + b_attn  -> bf16
  gemm_bt<EPI_BF16><<<dim3(3072 / 128, M_TOK / 128), blk, 0, stream>>>(
      Abuf, wqkvT, b_attn, nullptr, qkvb, M_TOK, 3072, 1024);

  // 4. split/reorder (+ q scale)
  reorder_qkv<<<dim3(T_SEQ / 64, 32), blk, 0, stream>>>(qkvb, Qb, Kbuf, Vtb);

  // 5. attention -> y bf16 (reuses Abuf)
  attn_fwd<<<dim3(T_SEQ / 64, 32), blk, 0, stream>>>(Qb, Kbuf, Vtb, Abuf);

  // 6. x1 = y @ W_proj + b_proj + x   (fp32 residual)
  gemm_bt<EPI_RES_F32><<<dim3(1024 / 128, M_TOK / 128), blk, 0, stream>>>(
      Abuf, wprojT, b_proj, x, x1, M_TOK, 1024, 1024);

  // 7. ln2 -> bf16 (reuses Abuf)
  ln_cast<<<M_TOK, blk, 0, stream>>>(x1, ln2_g, ln2_b, Abuf);

  // 8. h = gelu(ln2 @ W_fc + b_fc) -> bf16
  gemm_bt<EPI_GELU_BF16><<<dim3(4096 / 128, M_TOK / 128), blk, 0, stream>>>(
      Abuf, wfcT, b_fc, nullptr, hbuf, M_TOK, 4096, 1024);

  // 9. out = h @ W_fc2 + b_fc2 + x1   (fp32)
  gemm_bt<EPI_RES_F32><<<dim3(1024 / 128, M_TOK / 128), blk, 0, stream>>>(
      hbuf, wfc2T, b_fc2, x1, (float*)d_out, M_TOK, 1024, 4096);
}

// Round 2
// 477.651 us; speedup vs baseline: 1.2810x; 1.2810x over previous
//
#include <hip/hip_runtime.h>
#include <cstdint>
#include <cstddef>

// ---------------------------------------------------------------------------
// Transformer block on MI355X (gfx950), bf16 MFMA path.
// R2: attention rewritten with LDS-staged double-buffered K/V tiles
//     (global_load_lds w16, xor-swizzled), 1 barrier/iter, exp2 softmax,
//     heavy-first block order. proj/fc2 use 128x64 GEMM tiles (2 blocks/CU).
// ---------------------------------------------------------------------------

typedef unsigned short u16;
typedef short bf16x8 __attribute__((ext_vector_type(8)));
typedef float f32x4 __attribute__((ext_vector_type(4)));

#define C_EMBD 1024
#define T_SEQ  2048
#define N_BATCH 2
#define N_HEADS 16
#define HEAD_D 64
#define M_TOK  4096   // N_BATCH * T_SEQ

__device__ __forceinline__ u16 f2b(float f) {
  union { float f; unsigned u; } v; v.f = f;
  unsigned r = (v.u + 0x7fffu + ((v.u >> 16) & 1u)) >> 16;  // RNE
  return (u16)r;
}
__device__ __forceinline__ float b2f(u16 u) {
  union { unsigned u; float f; } v; v.u = ((unsigned)u) << 16;
  return v.f;
}
__device__ __forceinline__ void load_lds16(const void* g, void* l) {
  __builtin_amdgcn_global_load_lds(
      (const __attribute__((address_space(1))) void*)g,
      (__attribute__((address_space(3))) void*)l, 16, 0, 0);
}

// ---------------------------------------------------------------------------
// Weight transpose + cast: W[K][N] fp32 -> Wt[N][K] bf16
// ---------------------------------------------------------------------------
__global__ __launch_bounds__(256) void transpose_cast(
    const float* __restrict__ W, u16* __restrict__ Wt, int K, int N) {
  __shared__ float tile[32][33];
  const int n0 = blockIdx.x * 32, k0 = blockIdx.y * 32;
  const int tx = threadIdx.x & 31, ty = threadIdx.x >> 5;  // ty in [0,8)
#pragma unroll
  for (int i = 0; i < 32; i += 8)
    tile[ty + i][tx] = W[(size_t)(k0 + ty + i) * N + n0 + tx];
  __syncthreads();
#pragma unroll
  for (int i = 0; i < 32; i += 8)
    Wt[(size_t)(n0 + ty + i) * K + k0 + tx] = f2b(tile[tx][ty + i]);
}

// ---------------------------------------------------------------------------
// LayerNorm over rows of 1024 fp32 -> bf16 out. One block (256 thr) per row.
// ---------------------------------------------------------------------------
__global__ __launch_bounds__(256) void ln_cast(
    const float* __restrict__ X, const float* __restrict__ g,
    const float* __restrict__ b, u16* __restrict__ Y) {
  const int row = blockIdx.x;
  const int tid = threadIdx.x;
  const float4 v = ((const float4*)(X + (size_t)row * C_EMBD))[tid];
  float s = v.x + v.y + v.z + v.w;
  float ss = v.x * v.x + v.y * v.y + v.z * v.z + v.w * v.w;
#pragma unroll
  for (int off = 32; off > 0; off >>= 1) {
    s += __shfl_down(s, off, 64);
    ss += __shfl_down(ss, off, 64);
  }
  __shared__ float red[8];
  __shared__ float stats[2];
  const int wave = tid >> 6, lane = tid & 63;
  if (lane == 0) { red[wave] = s; red[4 + wave] = ss; }
  __syncthreads();
  if (tid == 0) {
    float S = red[0] + red[1] + red[2] + red[3];
    float SS = red[4] + red[5] + red[6] + red[7];
    float mu = S * (1.0f / C_EMBD);
    float var = SS * (1.0f / C_EMBD) - mu * mu;
    stats[0] = mu;
    stats[1] = rsqrtf(var + 1e-5f);
  }
  __syncthreads();
  const float mu = stats[0], rs = stats[1];
  const float4 gv = ((const float4*)g)[tid];
  const float4 bv = ((const float4*)b)[tid];
  ushort4 o;
  o.x = f2b((v.x - mu) * rs * gv.x + bv.x);
  o.y = f2b((v.y - mu) * rs * gv.y + bv.y);
  o.z = f2b((v.z - mu) * rs * gv.z + bv.z);
  o.w = f2b((v.w - mu) * rs * gv.w + bv.w);
  ((ushort4*)(Y + (size_t)row * C_EMBD))[tid] = o;
}

// ---------------------------------------------------------------------------
// GEMM: C[M,N] = A[M,K](bf16) * Bt[N,K](bf16)^T + bias. m97 structure.
// 256 thr = 4 waves (2x2). M-tile 128; N-tile = 64*TN/2 (TN=4 -> 128, TN=2 -> 64).
// ---------------------------------------------------------------------------
enum { EPI_BF16 = 0, EPI_RES_F32 = 1, EPI_GELU_BF16 = 2 };

template <int EPI, int TN>
__global__ __launch_bounds__(256) void gemm_bt(
    const u16* __restrict__ A, const u16* __restrict__ Bt,
    const float* __restrict__ bias, const float* __restrict__ res,
    void* __restrict__ Cout, int M, int N, int K) {
  __shared__ u16 As[128 * 32];
  __shared__ u16 Bs[TN * 32 * 32];
  const int tid = threadIdx.x;
  const int wave = tid >> 6, lane = tid & 63;
  const int quad = lane >> 4, l16 = lane & 15;
  const int m0 = blockIdx.y * 128, n0 = blockIdx.x * (TN * 32);
  const int wm = (wave >> 1) * 64, wn = (wave & 1) * (TN * 16);

  f32x4 acc[4][TN] = {};

  const int kTiles = K >> 5;
  for (int kt = 0; kt < kTiles; ++kt) {
    const int k0 = kt << 5;
#pragma unroll
    for (int i = 0; i < 2; ++i) {
      const int c = tid + i * 256;
      const int row = c >> 2, cc = (c & 3) * 8;
      load_lds16(A + (size_t)(m0 + row) * K + k0 + cc, &As[c * 8]);
    }
#pragma unroll
    for (int i = 0; i < (TN * 128) / 256; ++i) {
      const int c = tid + i * 256;
      const int row = c >> 2, cc = (c & 3) * 8;
      load_lds16(Bt + (size_t)(n0 + row) * K + k0 + cc, &Bs[c * 8]);
    }
    __syncthreads();
    bf16x8 aF[4], bF[TN];
#pragma unroll
    for (int t = 0; t < 4; ++t)
      aF[t] = *(const bf16x8*)&As[(wm + t * 16 + l16) * 32 + quad * 8];
#pragma unroll
    for (int t = 0; t < TN; ++t)
      bF[t] = *(const bf16x8*)&Bs[(wn + t * 16 + l16) * 32 + quad * 8];
#pragma unroll
    for (int tm = 0; tm < 4; ++tm)
#pragma unroll
      for (int tn = 0; tn < TN; ++tn)
        acc[tm][tn] = __builtin_amdgcn_mfma_f32_16x16x32_bf16(
            aF[tm], bF[tn], acc[tm][tn], 0, 0, 0);
    __syncthreads();
  }

  // epilogue: C/D layout col=lane&15, row=quad*4+reg
#pragma unroll
  for (int tm = 0; tm < 4; ++tm) {
#pragma unroll
    for (int r = 0; r < 4; ++r) {
      const int row = m0 + wm + tm * 16 + quad * 4 + r;
#pragma unroll
      for (int tn = 0; tn < TN; ++tn) {
        const int col = n0 + wn + tn * 16 + l16;
        float v = acc[tm][tn][r] + bias[col];
        if constexpr (EPI == EPI_RES_F32) {
          v += res[(size_t)row * N + col];
          ((float*)Cout)[(size_t)row * N + col] = v;
        } else if constexpr (EPI == EPI_GELU_BF16) {
          v = 0.5f * v * (1.0f + erff(v * 0.70710678118f));
          ((u16*)Cout)[(size_t)row * N + col] = f2b(v);
        } else {
          ((u16*)Cout)[(size_t)row * N + col] = f2b(v);
        }
      }
    }
  }
}

// ---------------------------------------------------------------------------
// Reorder qkv[M,3C] bf16 -> Q[BH,T,hd] (scaled 0.125*log2e), K[BH,T,hd],
// Vt[BH,hd,T]. Block: one (bh, 64-token tile). 256 threads.
// ---------------------------------------------------------------------------
#define Q_SCALE 0.18033688011112042f  // 1/sqrt(64) * log2(e)

__global__ __launch_bounds__(256) void reorder_qkv(
    const u16* __restrict__ qkv, u16* __restrict__ Q, u16* __restrict__ Kb,
    u16* __restrict__ Vt) {
  const int bh = blockIdx.y, tb = blockIdx.x;
  const int b = bh >> 4, h = bh & 15;
  const size_t row0 = (size_t)b * T_SEQ + tb * 64;  // qkv row base
  __shared__ u16 vt[64][68];
  const int tid = threadIdx.x;
#pragma unroll
  for (int i = 0; i < 4; ++i) {
    const int e = tid + i * 256;
    const int row = e >> 4, c4 = (e & 15) * 4;
    const u16* src = qkv + (row0 + row) * (3 * C_EMBD) + h * HEAD_D;
    ushort4 qv = *(const ushort4*)(src + c4);
    ushort4 qo;
    qo.x = f2b(b2f(qv.x) * Q_SCALE);
    qo.y = f2b(b2f(qv.y) * Q_SCALE);
    qo.z = f2b(b2f(qv.z) * Q_SCALE);
    qo.w = f2b(b2f(qv.w) * Q_SCALE);
    const size_t dst = ((size_t)bh * T_SEQ + tb * 64 + row) * HEAD_D + c4;
    *(ushort4*)(Q + dst) = qo;
    *(ushort4*)(Kb + dst) = *(const ushort4*)(src + C_EMBD + c4);
    ushort4 vv = *(const ushort4*)(src + 2 * C_EMBD + c4);
    vt[row][c4] = vv.x; vt[row][c4 + 1] = vv.y;
    vt[row][c4 + 2] = vv.z; vt[row][c4 + 3] = vv.w;
  }
  __syncthreads();
#pragma unroll
  for (int i = 0; i < 4; ++i) {
    const int e = tid + i * 256;
    const int d = e >> 4, t4 = (e & 15) * 4;
    ushort4 ov;
    ov.x = vt[t4][d]; ov.y = vt[t4 + 1][d];
    ov.z = vt[t4 + 2][d]; ov.w = vt[t4 + 3][d];
    *(ushort4*)(Vt + ((size_t)bh * HEAD_D + d) * T_SEQ + tb * 64 + t4) = ov;
  }
}

// ---------------------------------------------------------------------------
// Flash attention (causal), LDS-staged K/V with double buffering.
// Grid: x = qtile heavy-first, y = bh. 256 thr = 4 waves, wave w owns 16 Q rows.
// K-tile [64 keys][64 d] and V-tile [64 d][64 keys] staged via global_load_lds
// w16, xor-swizzled 16B chunks (row-stride 128B would alias all rows to bank 0;
// DMA dest is lane-linear so we swizzle the GLOBAL column per chunk instead).
// Softmax in exp2 domain (Q pre-scaled by 1/8*log2e).
// ---------------------------------------------------------------------------
__global__ __launch_bounds__(256) void attn_fwd(
    const u16* __restrict__ Q, const u16* __restrict__ Kb,
    const u16* __restrict__ Vt, u16* __restrict__ Y) {
  const int bh = blockIdx.y;
  const int qb = (int)gridDim.x - 1 - (int)blockIdx.x;  // heavy blocks first
  const int tid = threadIdx.x;
  const int wave = tid >> 6, lane = tid & 63;
  const int quad = lane >> 4, l16 = lane & 15;
  const int sw = l16 & 7;  // xor-swizzle key for frag reads
  const int q0 = qb * 64;
  const u16* Qp = Q + (size_t)bh * T_SEQ * HEAD_D;
  const u16* Kp = Kb + (size_t)bh * T_SEQ * HEAD_D;
  const u16* Vp = Vt + (size_t)bh * HEAD_D * T_SEQ;

  __shared__ u16 Ks[2][64 * 64];
  __shared__ u16 Vs[2][64 * 64];
  __shared__ u16 Pl[4][16 * 72];

  // stage one 64x64 u16 tile: chunk c -> row c>>3, LDS col8 c&7 holds
  // global col8 (c&7)^(row&7). LDS dest lane-linear (wave-uniform + lane*16).
  auto stage = [&](u16* dst, const u16* srcBase, size_t stride) {
#pragma unroll
    for (int i = 0; i < 2; ++i) {
      const int c = tid + i * 256;
      const int row = c >> 3;
      const int gc = (c & 7) ^ (row & 7);
      load_lds16(srcBase + (size_t)row * stride + gc * 8, dst + c * 8);
    }
  };

  // Q A-frags, kept across all K-tiles
  const int qrow = q0 + wave * 16 + l16;
  bf16x8 qF[2];
  qF[0] = *(const bf16x8*)&Qp[(size_t)qrow * HEAD_D + quad * 8];
  qF[1] = *(const bf16x8*)&Qp[(size_t)qrow * HEAD_D + 32 + quad * 8];

  f32x4 o[4] = {};
  float mrun[4], lrun[4];
#pragma unroll
  for (int r = 0; r < 4; ++r) { mrun[r] = -3e38f; lrun[r] = 0.0f; }

  stage(Ks[0], Kp, HEAD_D);
  stage(Vs[0], Vp, T_SEQ);

  int buf = 0;
  for (int kb = 0; kb <= qb; ++kb) {
    const int k0 = kb * 64;
    __syncthreads();  // drains this wave's DMA (vmcnt) + all waves' prior reads
    if (kb < qb) {    // prefetch next tile into the other buffer
      const int k1 = k0 + 64;
      stage(Ks[buf ^ 1], Kp + (size_t)k1 * HEAD_D, HEAD_D);
      stage(Vs[buf ^ 1], Vp + k1, T_SEQ);
    }
    // S = Q K^T (frag rows swizzle-decoded)
    f32x4 s[4] = {};
#pragma unroll
    for (int ks = 0; ks < 2; ++ks) {
#pragma unroll
      for (int nt = 0; nt < 4; ++nt) {
        const int krow = nt * 16 + l16;
        bf16x8 kF = *(const bf16x8*)
            &Ks[buf][krow * 64 + (((ks * 4 + quad) ^ sw) * 8)];
        s[nt] = __builtin_amdgcn_mfma_f32_16x16x32_bf16(qF[ks], kF, s[nt],
                                                        0, 0, 0);
      }
    }
    if (kb == qb) {  // causal mask, diagonal tile only
#pragma unroll
      for (int nt = 0; nt < 4; ++nt) {
        const int key = k0 + nt * 16 + l16;
#pragma unroll
        for (int r = 0; r < 4; ++r) {
          const int qq = q0 + wave * 16 + quad * 4 + r;
          if (key > qq) s[nt][r] = -3e38f;
        }
      }
    }
    // online softmax (exp2 domain), rows live per-quad; reduce over 16 lanes
#pragma unroll
    for (int r = 0; r < 4; ++r) {
      float m = fmaxf(fmaxf(s[0][r], s[1][r]), fmaxf(s[2][r], s[3][r]));
#pragma unroll
      for (int off = 1; off < 16; off <<= 1)
        m = fmaxf(m, __shfl_xor(m, off, 64));
      const float nm = fmaxf(mrun[r], m);
      const float alpha = __builtin_amdgcn_exp2f(mrun[r] - nm);
      mrun[r] = nm;
      float sum = 0.0f;
#pragma unroll
      for (int nt = 0; nt < 4; ++nt) {
        const float p = __builtin_amdgcn_exp2f(s[nt][r] - nm);
        s[nt][r] = p;
        sum += p;
      }
#pragma unroll
      for (int off = 1; off < 16; off <<= 1)
        sum += __shfl_xor(sum, off, 64);
      lrun[r] = lrun[r] * alpha + sum;
#pragma unroll
      for (int nt = 0; nt < 4; ++nt) o[nt][r] *= alpha;
    }
    // P: C-layout -> LDS (stride 72: 144B keeps b128 alignment, kills
    // quad-bank aliasing) -> A-layout. Per-wave private, no barrier needed.
#pragma unroll
    for (int nt = 0; nt < 4; ++nt)
#pragma unroll
      for (int r = 0; r < 4; ++r)
        Pl[wave][(quad * 4 + r) * 72 + nt * 16 + l16] = f2b(s[nt][r]);
#pragma unroll
    for (int ks = 0; ks < 2; ++ks) {
      bf16x8 aP = *(const bf16x8*)&Pl[wave][l16 * 72 + ks * 32 + quad * 8];
#pragma unroll
      for (int nt = 0; nt < 4; ++nt) {
        const int vrow = nt * 16 + l16;
        bf16x8 vF = *(const bf16x8*)
            &Vs[buf][vrow * 64 + (((ks * 4 + quad) ^ sw) * 8)];
        o[nt] = __builtin_amdgcn_mfma_f32_16x16x32_bf16(aP, vF, o[nt], 0, 0, 0);
      }
    }
    buf ^= 1;
  }

  // write O / l -> Y bf16 [B,T,C]
  const int b = bh >> 4, h = bh & 15;
  u16* yp = Y + ((size_t)(b * T_SEQ + q0 + wave * 16)) * C_EMBD + h * HEAD_D;
#pragma unroll
  for (int r = 0; r < 4; ++r) {
    const float rl = 1.0f / lrun[r];
#pragma unroll
    for (int nt = 0; nt < 4; ++nt)
      yp[(size_t)(quad * 4 + r) * C_EMBD + nt * 16 + l16] =
          f2b(o[nt][r] * rl);
  }
}

// ---------------------------------------------------------------------------
// Host side
// ---------------------------------------------------------------------------
extern "C" void kernel_launch(void* const* d_in, const int* in_sizes, int n_in,
                              void* d_out, int out_size, void* d_ws,
                              size_t ws_size, hipStream_t stream) {
  const float* x      = (const float*)d_in[0];
  const float* W_attn = (const float*)d_in[1];
  const float* b_attn = (const float*)d_in[2];
  const float* W_proj = (const float*)d_in[3];
  const float* b_proj = (const float*)d_in[4];
  const float* W_fc   = (const float*)d_in[5];
  const float* b_fc   = (const float*)d_in[6];
  const float* W_fc2  = (const float*)d_in[7];
  const float* b_fc2  = (const float*)d_in[8];
  const float* ln1_g  = (const float*)d_in[9];
  const float* ln1_b  = (const float*)d_in[10];
  const float* ln2_g  = (const float*)d_in[11];
  const float* ln2_b  = (const float*)d_in[12];

  u16* wqkvT = (u16*)d_ws;                            // [3072][1024] bf16
  u16* wprojT = wqkvT + (size_t)3072 * 1024;          // [1024][1024]
  u16* wfcT  = wprojT + (size_t)1024 * 1024;          // [4096][1024]
  u16* wfc2T = wfcT + (size_t)4096 * 1024;            // [1024][4096]
  u16* Abuf  = wfc2T + (size_t)1024 * 4096;           // [4096][1024] bf16
  float* x1  = (float*)(Abuf + (size_t)M_TOK * C_EMBD);  // [4096][1024] f32
  u16* hbuf  = (u16*)(x1 + (size_t)M_TOK * C_EMBD);   // [4096][4096] bf16
  u16* qkvb  = hbuf;                                  // [4096][3072] (dead before h)
  u16* Qb    = hbuf + (size_t)M_TOK * 4096;           // [32][2048][64]
  u16* Kbuf  = Qb + (size_t)32 * T_SEQ * HEAD_D;
  u16* Vtb   = Kbuf + (size_t)32 * T_SEQ * HEAD_D;

  const dim3 blk(256);

  transpose_cast<<<dim3(3072 / 32, 1024 / 32), blk, 0, stream>>>(W_attn, wqkvT, 1024, 3072);
  transpose_cast<<<dim3(1024 / 32, 1024 / 32), blk, 0, stream>>>(W_proj, wprojT, 1024, 1024);
  transpose_cast<<<dim3(4096 / 32, 1024 / 32), blk, 0, stream>>>(W_fc, wfcT, 1024, 4096);
  transpose_cast<<<dim3(1024 / 32, 4096 / 32), blk, 0, stream>>>(W_fc2, wfc2T, 4096, 1024);

  ln_cast<<<M_TOK, blk, 0, stream>>>(x, ln1_g, ln1_b, Abuf);

  gemm_bt<EPI_BF16, 4><<<dim3(3072 / 128, M_TOK / 128), blk, 0, stream>>>(
      Abuf, wqkvT, b_attn, nullptr, qkvb, M_TOK, 3072, 1024);

  reorder_qkv<<<dim3(T_SEQ / 64, 32), blk, 0, stream>>>(qkvb, Qb, Kbuf, Vtb);

  attn_fwd<<<dim3(T_SEQ / 64, 32), blk, 0, stream>>>(Qb, Kbuf, Vtb, Abuf);

  gemm_bt<EPI_RES_F32, 2><<<dim3(1024 / 64, M_TOK / 128), blk, 0, stream>>>(
      Abuf, wprojT, b_proj, x, x1, M_TOK, 1024, 1024);

  ln_cast<<<M_TOK, blk, 0, stream>>>(x1, ln2_g, ln2_b, Abuf);

  gemm_bt<EPI_GELU_BF16, 4><<<dim3(4096 / 128, M_TOK / 128), blk, 0, stream>>>(
      Abuf, wfcT, b_fc, nullptr, hbuf, M_TOK, 4096, 1024);

  gemm_bt<EPI_RES_F32, 2><<<dim3(1024 / 64, M_TOK / 128), blk, 0, stream>>>(
      hbuf, wfc2T, b_fc2, x1, (float*)d_out, M_TOK, 1024, 4096);
}

// Round 3
// 429.256 us; speedup vs baseline: 1.4254x; 1.1127x over previous
//
#include <hip/hip_runtime.h>
#include <cstdint>
#include <cstddef>

// ---------------------------------------------------------------------------
// Transformer block on MI355X (gfx950), bf16 MFMA path.
// R3: attention triangle-paired — each block does q-tiles (31-pair) and
//     (pair) => uniform 33 K-iters/block, 512 blocks. Kills causal imbalance.
// ---------------------------------------------------------------------------

typedef unsigned short u16;
typedef short bf16x8 __attribute__((ext_vector_type(8)));
typedef float f32x4 __attribute__((ext_vector_type(4)));

#define C_EMBD 1024
#define T_SEQ  2048
#define N_BATCH 2
#define N_HEADS 16
#define HEAD_D 64
#define M_TOK  4096   // N_BATCH * T_SEQ

__device__ __forceinline__ u16 f2b(float f) {
  union { float f; unsigned u; } v; v.f = f;
  unsigned r = (v.u + 0x7fffu + ((v.u >> 16) & 1u)) >> 16;  // RNE
  return (u16)r;
}
__device__ __forceinline__ float b2f(u16 u) {
  union { unsigned u; float f; } v; v.u = ((unsigned)u) << 16;
  return v.f;
}
__device__ __forceinline__ void load_lds16(const void* g, void* l) {
  __builtin_amdgcn_global_load_lds(
      (const __attribute__((address_space(1))) void*)g,
      (__attribute__((address_space(3))) void*)l, 16, 0, 0);
}

// ---------------------------------------------------------------------------
// Weight transpose + cast: W[K][N] fp32 -> Wt[N][K] bf16
// ---------------------------------------------------------------------------
__global__ __launch_bounds__(256) void transpose_cast(
    const float* __restrict__ W, u16* __restrict__ Wt, int K, int N) {
  __shared__ float tile[32][33];
  const int n0 = blockIdx.x * 32, k0 = blockIdx.y * 32;
  const int tx = threadIdx.x & 31, ty = threadIdx.x >> 5;  // ty in [0,8)
#pragma unroll
  for (int i = 0; i < 32; i += 8)
    tile[ty + i][tx] = W[(size_t)(k0 + ty + i) * N + n0 + tx];
  __syncthreads();
#pragma unroll
  for (int i = 0; i < 32; i += 8)
    Wt[(size_t)(n0 + ty + i) * K + k0 + tx] = f2b(tile[tx][ty + i]);
}

// ---------------------------------------------------------------------------
// LayerNorm over rows of 1024 fp32 -> bf16 out. One block (256 thr) per row.
// ---------------------------------------------------------------------------
__global__ __launch_bounds__(256) void ln_cast(
    const float* __restrict__ X, const float* __restrict__ g,
    const float* __restrict__ b, u16* __restrict__ Y) {
  const int row = blockIdx.x;
  const int tid = threadIdx.x;
  const float4 v = ((const float4*)(X + (size_t)row * C_EMBD))[tid];
  float s = v.x + v.y + v.z + v.w;
  float ss = v.x * v.x + v.y * v.y + v.z * v.z + v.w * v.w;
#pragma unroll
  for (int off = 32; off > 0; off >>= 1) {
    s += __shfl_down(s, off, 64);
    ss += __shfl_down(ss, off, 64);
  }
  __shared__ float red[8];
  __shared__ float stats[2];
  const int wave = tid >> 6, lane = tid & 63;
  if (lane == 0) { red[wave] = s; red[4 + wave] = ss; }
  __syncthreads();
  if (tid == 0) {
    float S = red[0] + red[1] + red[2] + red[3];
    float SS = red[4] + red[5] + red[6] + red[7];
    float mu = S * (1.0f / C_EMBD);
    float var = SS * (1.0f / C_EMBD) - mu * mu;
    stats[0] = mu;
    stats[1] = rsqrtf(var + 1e-5f);
  }
  __syncthreads();
  const float mu = stats[0], rs = stats[1];
  const float4 gv = ((const float4*)g)[tid];
  const float4 bv = ((const float4*)b)[tid];
  ushort4 o;
  o.x = f2b((v.x - mu) * rs * gv.x + bv.x);
  o.y = f2b((v.y - mu) * rs * gv.y + bv.y);
  o.z = f2b((v.z - mu) * rs * gv.z + bv.z);
  o.w = f2b((v.w - mu) * rs * gv.w + bv.w);
  ((ushort4*)(Y + (size_t)row * C_EMBD))[tid] = o;
}

// ---------------------------------------------------------------------------
// GEMM: C[M,N] = A[M,K](bf16) * Bt[N,K](bf16)^T + bias. m97 structure.
// 256 thr = 4 waves (2x2). M-tile 128; N-tile = 64*TN/2 (TN=4 -> 128, TN=2 -> 64).
// ---------------------------------------------------------------------------
enum { EPI_BF16 = 0, EPI_RES_F32 = 1, EPI_GELU_BF16 = 2 };

template <int EPI, int TN>
__global__ __launch_bounds__(256) void gemm_bt(
    const u16* __restrict__ A, const u16* __restrict__ Bt,
    const float* __restrict__ bias, const float* __restrict__ res,
    void* __restrict__ Cout, int M, int N, int K) {
  __shared__ u16 As[128 * 32];
  __shared__ u16 Bs[TN * 32 * 32];
  const int tid = threadIdx.x;
  const int wave = tid >> 6, lane = tid & 63;
  const int quad = lane >> 4, l16 = lane & 15;
  const int m0 = blockIdx.y * 128, n0 = blockIdx.x * (TN * 32);
  const int wm = (wave >> 1) * 64, wn = (wave & 1) * (TN * 16);

  f32x4 acc[4][TN] = {};

  const int kTiles = K >> 5;
  for (int kt = 0; kt < kTiles; ++kt) {
    const int k0 = kt << 5;
#pragma unroll
    for (int i = 0; i < 2; ++i) {
      const int c = tid + i * 256;
      const int row = c >> 2, cc = (c & 3) * 8;
      load_lds16(A + (size_t)(m0 + row) * K + k0 + cc, &As[c * 8]);
    }
#pragma unroll
    for (int i = 0; i < (TN * 128) / 256; ++i) {
      const int c = tid + i * 256;
      const int row = c >> 2, cc = (c & 3) * 8;
      load_lds16(Bt + (size_t)(n0 + row) * K + k0 + cc, &Bs[c * 8]);
    }
    __syncthreads();
    bf16x8 aF[4], bF[TN];
#pragma unroll
    for (int t = 0; t < 4; ++t)
      aF[t] = *(const bf16x8*)&As[(wm + t * 16 + l16) * 32 + quad * 8];
#pragma unroll
    for (int t = 0; t < TN; ++t)
      bF[t] = *(const bf16x8*)&Bs[(wn + t * 16 + l16) * 32 + quad * 8];
#pragma unroll
    for (int tm = 0; tm < 4; ++tm)
#pragma unroll
      for (int tn = 0; tn < TN; ++tn)
        acc[tm][tn] = __builtin_amdgcn_mfma_f32_16x16x32_bf16(
            aF[tm], bF[tn], acc[tm][tn], 0, 0, 0);
    __syncthreads();
  }

  // epilogue: C/D layout col=lane&15, row=quad*4+reg
#pragma unroll
  for (int tm = 0; tm < 4; ++tm) {
#pragma unroll
    for (int r = 0; r < 4; ++r) {
      const int row = m0 + wm + tm * 16 + quad * 4 + r;
#pragma unroll
      for (int tn = 0; tn < TN; ++tn) {
        const int col = n0 + wn + tn * 16 + l16;
        float v = acc[tm][tn][r] + bias[col];
        if constexpr (EPI == EPI_RES_F32) {
          v += res[(size_t)row * N + col];
          ((float*)Cout)[(size_t)row * N + col] = v;
        } else if constexpr (EPI == EPI_GELU_BF16) {
          v = 0.5f * v * (1.0f + erff(v * 0.70710678118f));
          ((u16*)Cout)[(size_t)row * N + col] = f2b(v);
        } else {
          ((u16*)Cout)[(size_t)row * N + col] = f2b(v);
        }
      }
    }
  }
}

// ---------------------------------------------------------------------------
// Reorder qkv[M,3C] bf16 -> Q[BH,T,hd] (scaled 0.125*log2e), K[BH,T,hd],
// Vt[BH,hd,T]. Block: one (bh, 64-token tile). 256 threads.
// ---------------------------------------------------------------------------
#define Q_SCALE 0.18033688011112042f  // 1/sqrt(64) * log2(e)

__global__ __launch_bounds__(256) void reorder_qkv(
    const u16* __restrict__ qkv, u16* __restrict__ Q, u16* __restrict__ Kb,
    u16* __restrict__ Vt) {
  const int bh = blockIdx.y, tb = blockIdx.x;
  const int b = bh >> 4, h = bh & 15;
  const size_t row0 = (size_t)b * T_SEQ + tb * 64;  // qkv row base
  __shared__ u16 vt[64][68];
  const int tid = threadIdx.x;
#pragma unroll
  for (int i = 0; i < 4; ++i) {
    const int e = tid + i * 256;
    const int row = e >> 4, c4 = (e & 15) * 4;
    const u16* src = qkv + (row0 + row) * (3 * C_EMBD) + h * HEAD_D;
    ushort4 qv = *(const ushort4*)(src + c4);
    ushort4 qo;
    qo.x = f2b(b2f(qv.x) * Q_SCALE);
    qo.y = f2b(b2f(qv.y) * Q_SCALE);
    qo.z = f2b(b2f(qv.z) * Q_SCALE);
    qo.w = f2b(b2f(qv.w) * Q_SCALE);
    const size_t dst = ((size_t)bh * T_SEQ + tb * 64 + row) * HEAD_D + c4;
    *(ushort4*)(Q + dst) = qo;
    *(ushort4*)(Kb + dst) = *(const ushort4*)(src + C_EMBD + c4);
    ushort4 vv = *(const ushort4*)(src + 2 * C_EMBD + c4);
    vt[row][c4] = vv.x; vt[row][c4 + 1] = vv.y;
    vt[row][c4 + 2] = vv.z; vt[row][c4 + 3] = vv.w;
  }
  __syncthreads();
#pragma unroll
  for (int i = 0; i < 4; ++i) {
    const int e = tid + i * 256;
    const int d = e >> 4, t4 = (e & 15) * 4;
    ushort4 ov;
    ov.x = vt[t4][d]; ov.y = vt[t4 + 1][d];
    ov.z = vt[t4 + 2][d]; ov.w = vt[t4 + 3][d];
    *(ushort4*)(Vt + ((size_t)bh * HEAD_D + d) * T_SEQ + tb * 64 + t4) = ov;
  }
}

// ---------------------------------------------------------------------------
// Flash attention (causal), LDS-staged double-buffered K/V, triangle-paired:
// block = (pair, bh); processes q-tile (31-pair) then q-tile (pair) =>
// exactly NT+1 = 33 K-iters per block, grid 16x32 = 512 uniform blocks.
// ---------------------------------------------------------------------------
__global__ __launch_bounds__(256) void attn_fwd(
    const u16* __restrict__ Q, const u16* __restrict__ Kb,
    const u16* __restrict__ Vt, u16* __restrict__ Y) {
  const int bh = blockIdx.y;
  const int pair = blockIdx.x;
  const int nqt = (int)(T_SEQ / 64);
  const int tid = threadIdx.x;
  const int wave = tid >> 6, lane = tid & 63;
  const int quad = lane >> 4, l16 = lane & 15;
  const int sw = l16 & 7;  // xor-swizzle key for frag reads
  const u16* Qp = Q + (size_t)bh * T_SEQ * HEAD_D;
  const u16* Kp = Kb + (size_t)bh * T_SEQ * HEAD_D;
  const u16* Vp = Vt + (size_t)bh * HEAD_D * T_SEQ;

  __shared__ u16 Ks[2][64 * 64];
  __shared__ u16 Vs[2][64 * 64];
  __shared__ u16 Pl[4][16 * 72];

  // stage one 64x64 u16 tile: chunk c -> row c>>3, LDS col8 c&7 holds
  // global col8 (c&7)^(row&7). LDS dest lane-linear (wave-uniform + lane*16).
  auto stage = [&](u16* dst, const u16* srcBase, size_t stride) {
#pragma unroll
    for (int i = 0; i < 2; ++i) {
      const int c = tid + i * 256;
      const int row = c >> 3;
      const int gc = (c & 7) ^ (row & 7);
      load_lds16(srcBase + (size_t)row * stride + gc * 8, dst + c * 8);
    }
  };

  const int b = bh >> 4, h = bh & 15;

#pragma unroll 1
  for (int phase = 0; phase < 2; ++phase) {
    const int qb = phase == 0 ? (nqt - 1 - pair) : pair;
    const int q0 = qb * 64;

    if (phase == 1) __syncthreads();  // protect Ks/Vs from prior phase readers

    // Q A-frags for this phase
    const int qrow = q0 + wave * 16 + l16;
    bf16x8 qF[2];
    qF[0] = *(const bf16x8*)&Qp[(size_t)qrow * HEAD_D + quad * 8];
    qF[1] = *(const bf16x8*)&Qp[(size_t)qrow * HEAD_D + 32 + quad * 8];

    f32x4 o[4] = {};
    float mrun[4], lrun[4];
#pragma unroll
    for (int r = 0; r < 4; ++r) { mrun[r] = -3e38f; lrun[r] = 0.0f; }

    stage(Ks[0], Kp, HEAD_D);
    stage(Vs[0], Vp, T_SEQ);

    int buf = 0;
    for (int kb = 0; kb <= qb; ++kb) {
      const int k0 = kb * 64;
      __syncthreads();  // drains DMA (vmcnt) + all waves' prior-buffer reads
      if (kb < qb) {    // prefetch next tile into the other buffer
        const int k1 = k0 + 64;
        stage(Ks[buf ^ 1], Kp + (size_t)k1 * HEAD_D, HEAD_D);
        stage(Vs[buf ^ 1], Vp + k1, T_SEQ);
      }
      // S = Q K^T (frag rows swizzle-decoded)
      f32x4 s[4] = {};
#pragma unroll
      for (int ks = 0; ks < 2; ++ks) {
#pragma unroll
        for (int nt = 0; nt < 4; ++nt) {
          const int krow = nt * 16 + l16;
          bf16x8 kF = *(const bf16x8*)
              &Ks[buf][krow * 64 + (((ks * 4 + quad) ^ sw) * 8)];
          s[nt] = __builtin_amdgcn_mfma_f32_16x16x32_bf16(qF[ks], kF, s[nt],
                                                          0, 0, 0);
        }
      }
      if (kb == qb) {  // causal mask, diagonal tile only
#pragma unroll
        for (int nt = 0; nt < 4; ++nt) {
          const int key = k0 + nt * 16 + l16;
#pragma unroll
          for (int r = 0; r < 4; ++r) {
            const int qq = q0 + wave * 16 + quad * 4 + r;
            if (key > qq) s[nt][r] = -3e38f;
          }
        }
      }
      // online softmax (exp2 domain), rows per-quad; reduce over 16 lanes
#pragma unroll
      for (int r = 0; r < 4; ++r) {
        float m = fmaxf(fmaxf(s[0][r], s[1][r]), fmaxf(s[2][r], s[3][r]));
#pragma unroll
        for (int off = 1; off < 16; off <<= 1)
          m = fmaxf(m, __shfl_xor(m, off, 64));
        const float nm = fmaxf(mrun[r], m);
        const float alpha = __builtin_amdgcn_exp2f(mrun[r] - nm);
        mrun[r] = nm;
        float sum = 0.0f;
#pragma unroll
        for (int nt = 0; nt < 4; ++nt) {
          const float p = __builtin_amdgcn_exp2f(s[nt][r] - nm);
          s[nt][r] = p;
          sum += p;
        }
#pragma unroll
        for (int off = 1; off < 16; off <<= 1)
          sum += __shfl_xor(sum, off, 64);
        lrun[r] = lrun[r] * alpha + sum;
#pragma unroll
        for (int nt = 0; nt < 4; ++nt) o[nt][r] *= alpha;
      }
      // P: C-layout -> LDS (stride 72 kills quad-bank aliasing) -> A-layout.
#pragma unroll
      for (int nt = 0; nt < 4; ++nt)
#pragma unroll
        for (int r = 0; r < 4; ++r)
          Pl[wave][(quad * 4 + r) * 72 + nt * 16 + l16] = f2b(s[nt][r]);
#pragma unroll
      for (int ks = 0; ks < 2; ++ks) {
        bf16x8 aP = *(const bf16x8*)&Pl[wave][l16 * 72 + ks * 32 + quad * 8];
#pragma unroll
        for (int nt = 0; nt < 4; ++nt) {
          const int vrow = nt * 16 + l16;
          bf16x8 vF = *(const bf16x8*)
              &Vs[buf][vrow * 64 + (((ks * 4 + quad) ^ sw) * 8)];
          o[nt] =
              __builtin_amdgcn_mfma_f32_16x16x32_bf16(aP, vF, o[nt], 0, 0, 0);
        }
      }
      buf ^= 1;
    }

    // write O / l -> Y bf16 [B,T,C]
    u16* yp =
        Y + ((size_t)(b * T_SEQ + q0 + wave * 16)) * C_EMBD + h * HEAD_D;
#pragma unroll
    for (int r = 0; r < 4; ++r) {
      const float rl = 1.0f / lrun[r];
#pragma unroll
      for (int nt = 0; nt < 4; ++nt)
        yp[(size_t)(quad * 4 + r) * C_EMBD + nt * 16 + l16] =
            f2b(o[nt][r] * rl);
    }
  }
}

// ---------------------------------------------------------------------------
// Host side
// ---------------------------------------------------------------------------
extern "C" void kernel_launch(void* const* d_in, const int* in_sizes, int n_in,
                              void* d_out, int out_size, void* d_ws,
                              size_t ws_size, hipStream_t stream) {
  const float* x      = (const float*)d_in[0];
  const float* W_attn = (const float*)d_in[1];
  const float* b_attn = (const float*)d_in[2];
  const float* W_proj = (const float*)d_in[3];
  const float* b_proj = (const float*)d_in[4];
  const float* W_fc   = (const float*)d_in[5];
  const float* b_fc   = (const float*)d_in[6];
  const float* W_fc2  = (const float*)d_in[7];
  const float* b_fc2  = (const float*)d_in[8];
  const float* ln1_g  = (const float*)d_in[9];
  const float* ln1_b  = (const float*)d_in[10];
  const float* ln2_g  = (const float*)d_in[11];
  const float* ln2_b  = (const float*)d_in[12];

  u16* wqkvT = (u16*)d_ws;                            // [3072][1024] bf16
  u16* wprojT = wqkvT + (size_t)3072 * 1024;          // [1024][1024]
  u16* wfcT  = wprojT + (size_t)1024 * 1024;          // [4096][1024]
  u16* wfc2T = wfcT + (size_t)4096 * 1024;            // [1024][4096]
  u16* Abuf  = wfc2T + (size_t)1024 * 4096;           // [4096][1024] bf16
  float* x1  = (float*)(Abuf + (size_t)M_TOK * C_EMBD);  // [4096][1024] f32
  u16* hbuf  = (u16*)(x1 + (size_t)M_TOK * C_EMBD);   // [4096][4096] bf16
  u16* qkvb  = hbuf;                                  // [4096][3072] (dead before h)
  u16* Qb    = hbuf + (size_t)M_TOK * 4096;           // [32][2048][64]
  u16* Kbuf  = Qb + (size_t)32 * T_SEQ * HEAD_D;
  u16* Vtb   = Kbuf + (size_t)32 * T_SEQ * HEAD_D;

  const dim3 blk(256);

  transpose_cast<<<dim3(3072 / 32, 1024 / 32), blk, 0, stream>>>(W_attn, wqkvT, 1024, 3072);
  transpose_cast<<<dim3(1024 / 32, 1024 / 32), blk, 0, stream>>>(W_proj, wprojT, 1024, 1024);
  transpose_cast<<<dim3(4096 / 32, 1024 / 32), blk, 0, stream>>>(W_fc, wfcT, 1024, 4096);
  transpose_cast<<<dim3(1024 / 32, 4096 / 32), blk, 0, stream>>>(W_fc2, wfc2T, 4096, 1024);

  ln_cast<<<M_TOK, blk, 0, stream>>>(x, ln1_g, ln1_b, Abuf);

  gemm_bt<EPI_BF16, 4><<<dim3(3072 / 128, M_TOK / 128), blk, 0, stream>>>(
      Abuf, wqkvT, b_attn, nullptr, qkvb, M_TOK, 3072, 1024);

  reorder_qkv<<<dim3(T_SEQ / 64, 32), blk, 0, stream>>>(qkvb, Qb, Kbuf, Vtb);

  attn_fwd<<<dim3(T_SEQ / 128, 32), blk, 0, stream>>>(Qb, Kbuf, Vtb, Abuf);

  gemm_bt<EPI_RES_F32, 2><<<dim3(1024 / 64, M_TOK / 128), blk, 0, stream>>>(
      Abuf, wprojT, b_proj, x, x1, M_TOK, 1024, 1024);

  ln_cast<<<M_TOK, blk, 0, stream>>>(x1, ln2_g, ln2_b, Abuf);

  gemm_bt<EPI_GELU_BF16, 4><<<dim3(4096 / 128, M_TOK / 128), blk, 0, stream>>>(
      Abuf, wfcT, b_fc, nullptr, hbuf, M_TOK, 4096, 1024);

  gemm_bt<EPI_RES_F32, 2><<<dim3(1024 / 64, M_TOK / 128), blk, 0, stream>>>(
      hbuf, wfc2T, b_fc2, x1, (float*)d_out, M_TOK, 1024, 4096);
}

// Round 4
// 420.091 us; speedup vs baseline: 1.4565x; 1.0218x over previous
//
#include <hip/hip_runtime.h>
#include <cstdint>
#include <cstddef>

// ---------------------------------------------------------------------------
// Transformer block on MI355X (gfx950), bf16 MFMA path.
// R4: (1) proj/fc2 -> TN=4 split-K=2 (m97 shape, 512 blocks) + float4 reduce;
//     (2) attention softmax transposed: S^T = mfma(K,Q), O^T = mfma(V^T,P^T)
//         -> per-lane scalar m/l, 2 shfls per reduction instead of 32.
// ---------------------------------------------------------------------------

typedef unsigned short u16;
typedef short bf16x8 __attribute__((ext_vector_type(8)));
typedef float f32x4 __attribute__((ext_vector_type(4)));

#define C_EMBD 1024
#define T_SEQ  2048
#define N_BATCH 2
#define N_HEADS 16
#define HEAD_D 64
#define M_TOK  4096   // N_BATCH * T_SEQ

__device__ __forceinline__ u16 f2b(float f) {
  union { float f; unsigned u; } v; v.f = f;
  unsigned r = (v.u + 0x7fffu + ((v.u >> 16) & 1u)) >> 16;  // RNE
  return (u16)r;
}
__device__ __forceinline__ float b2f(u16 u) {
  union { unsigned u; float f; } v; v.u = ((unsigned)u) << 16;
  return v.f;
}
__device__ __forceinline__ void load_lds16(const void* g, void* l) {
  __builtin_amdgcn_global_load_lds(
      (const __attribute__((address_space(1))) void*)g,
      (__attribute__((address_space(3))) void*)l, 16, 0, 0);
}

// ---------------------------------------------------------------------------
// Weight transpose + cast: W[K][N] fp32 -> Wt[N][K] bf16
// ---------------------------------------------------------------------------
__global__ __launch_bounds__(256) void transpose_cast(
    const float* __restrict__ W, u16* __restrict__ Wt, int K, int N) {
  __shared__ float tile[32][33];
  const int n0 = blockIdx.x * 32, k0 = blockIdx.y * 32;
  const int tx = threadIdx.x & 31, ty = threadIdx.x >> 5;  // ty in [0,8)
#pragma unroll
  for (int i = 0; i < 32; i += 8)
    tile[ty + i][tx] = W[(size_t)(k0 + ty + i) * N + n0 + tx];
  __syncthreads();
#pragma unroll
  for (int i = 0; i < 32; i += 8)
    Wt[(size_t)(n0 + ty + i) * K + k0 + tx] = f2b(tile[tx][ty + i]);
}

// ---------------------------------------------------------------------------
// LayerNorm over rows of 1024 fp32 -> bf16 out. One block (256 thr) per row.
// ---------------------------------------------------------------------------
__global__ __launch_bounds__(256) void ln_cast(
    const float* __restrict__ X, const float* __restrict__ g,
    const float* __restrict__ b, u16* __restrict__ Y) {
  const int row = blockIdx.x;
  const int tid = threadIdx.x;
  const float4 v = ((const float4*)(X + (size_t)row * C_EMBD))[tid];
  float s = v.x + v.y + v.z + v.w;
  float ss = v.x * v.x + v.y * v.y + v.z * v.z + v.w * v.w;
#pragma unroll
  for (int off = 32; off > 0; off >>= 1) {
    s += __shfl_down(s, off, 64);
    ss += __shfl_down(ss, off, 64);
  }
  __shared__ float red[8];
  __shared__ float stats[2];
  const int wave = tid >> 6, lane = tid & 63;
  if (lane == 0) { red[wave] = s; red[4 + wave] = ss; }
  __syncthreads();
  if (tid == 0) {
    float S = red[0] + red[1] + red[2] + red[3];
    float SS = red[4] + red[5] + red[6] + red[7];
    float mu = S * (1.0f / C_EMBD);
    float var = SS * (1.0f / C_EMBD) - mu * mu;
    stats[0] = mu;
    stats[1] = rsqrtf(var + 1e-5f);
  }
  __syncthreads();
  const float mu = stats[0], rs = stats[1];
  const float4 gv = ((const float4*)g)[tid];
  const float4 bv = ((const float4*)b)[tid];
  ushort4 o;
  o.x = f2b((v.x - mu) * rs * gv.x + bv.x);
  o.y = f2b((v.y - mu) * rs * gv.y + bv.y);
  o.z = f2b((v.z - mu) * rs * gv.z + bv.z);
  o.w = f2b((v.w - mu) * rs * gv.w + bv.w);
  ((ushort4*)(Y + (size_t)row * C_EMBD))[tid] = o;
}

// ---------------------------------------------------------------------------
// GEMM: C[M,N] = A[M,K](bf16) * Bt[N,K](bf16)^T + bias. m97 structure.
// 256 thr = 4 waves (2x2). M-tile 128; N-tile 64*TN/2. SPLIT=2: blockIdx.z
// selects K-half, partial f32 written (no bias/res) to Cout/Cout2 by z.
// ---------------------------------------------------------------------------
enum { EPI_BF16 = 0, EPI_RES_F32 = 1, EPI_GELU_BF16 = 2, EPI_PART = 3 };

template <int EPI, int TN, int SPLIT>
__global__ __launch_bounds__(256) void gemm_bt(
    const u16* __restrict__ A, const u16* __restrict__ Bt,
    const float* __restrict__ bias, const float* __restrict__ res,
    void* __restrict__ Cout, void* __restrict__ Cout2, int M, int N, int K) {
  __shared__ u16 As[128 * 32];
  __shared__ u16 Bs[TN * 32 * 32];
  const int tid = threadIdx.x;
  const int wave = tid >> 6, lane = tid & 63;
  const int quad = lane >> 4, l16 = lane & 15;
  const int m0 = blockIdx.y * 128, n0 = blockIdx.x * (TN * 32);
  const int wm = (wave >> 1) * 64, wn = (wave & 1) * (TN * 16);

  f32x4 acc[4][TN] = {};

  const int kTiles = (K >> 5) / SPLIT;
  const int kt0 = (SPLIT == 2) ? (int)blockIdx.z * kTiles : 0;
  for (int kt = kt0; kt < kt0 + kTiles; ++kt) {
    const int k0 = kt << 5;
#pragma unroll
    for (int i = 0; i < 2; ++i) {
      const int c = tid + i * 256;
      const int row = c >> 2, cc = (c & 3) * 8;
      load_lds16(A + (size_t)(m0 + row) * K + k0 + cc, &As[c * 8]);
    }
#pragma unroll
    for (int i = 0; i < (TN * 128) / 256; ++i) {
      const int c = tid + i * 256;
      const int row = c >> 2, cc = (c & 3) * 8;
      load_lds16(Bt + (size_t)(n0 + row) * K + k0 + cc, &Bs[c * 8]);
    }
    __syncthreads();
    bf16x8 aF[4], bF[TN];
#pragma unroll
    for (int t = 0; t < 4; ++t)
      aF[t] = *(const bf16x8*)&As[(wm + t * 16 + l16) * 32 + quad * 8];
#pragma unroll
    for (int t = 0; t < TN; ++t)
      bF[t] = *(const bf16x8*)&Bs[(wn + t * 16 + l16) * 32 + quad * 8];
#pragma unroll
    for (int tm = 0; tm < 4; ++tm)
#pragma unroll
      for (int tn = 0; tn < TN; ++tn)
        acc[tm][tn] = __builtin_amdgcn_mfma_f32_16x16x32_bf16(
            aF[tm], bF[tn], acc[tm][tn], 0, 0, 0);
    __syncthreads();
  }

  float* Pz = (float*)((SPLIT == 2 && blockIdx.z == 1) ? Cout2 : Cout);
  // epilogue: C/D layout col=lane&15, row=quad*4+reg
#pragma unroll
  for (int tm = 0; tm < 4; ++tm) {
#pragma unroll
    for (int r = 0; r < 4; ++r) {
      const int row = m0 + wm + tm * 16 + quad * 4 + r;
#pragma unroll
      for (int tn = 0; tn < TN; ++tn) {
        const int col = n0 + wn + tn * 16 + l16;
        if constexpr (EPI == EPI_PART) {
          Pz[(size_t)row * N + col] = acc[tm][tn][r];
        } else {
          float v = acc[tm][tn][r] + bias[col];
          if constexpr (EPI == EPI_RES_F32) {
            v += res[(size_t)row * N + col];
            ((float*)Cout)[(size_t)row * N + col] = v;
          } else if constexpr (EPI == EPI_GELU_BF16) {
            v = 0.5f * v * (1.0f + erff(v * 0.70710678118f));
            ((u16*)Cout)[(size_t)row * N + col] = f2b(v);
          } else {
            ((u16*)Cout)[(size_t)row * N + col] = f2b(v);
          }
        }
      }
    }
  }
}

// ---------------------------------------------------------------------------
// reduce: out = P0 + P1 + bias[col] + res. N fixed 1024. float4 per thread.
// ---------------------------------------------------------------------------
__global__ __launch_bounds__(256) void reduce_add(
    const float* __restrict__ P0, const float* __restrict__ P1,
    const float* __restrict__ bias, const float* __restrict__ res,
    float* __restrict__ out) {
  const int idx = blockIdx.x * 256 + threadIdx.x;  // float4 index
  const float4 a = ((const float4*)P0)[idx];
  const float4 b = ((const float4*)P1)[idx];
  const float4 c = ((const float4*)res)[idx];
  const float4 g = ((const float4*)bias)[idx & 255];  // 1024/4 = 256
  float4 o;
  o.x = a.x + b.x + c.x + g.x;
  o.y = a.y + b.y + c.y + g.y;
  o.z = a.z + b.z + c.z + g.z;
  o.w = a.w + b.w + c.w + g.w;
  ((float4*)out)[idx] = o;
}

// ---------------------------------------------------------------------------
// Reorder qkv[M,3C] bf16 -> Q[BH,T,hd] (scaled 0.125*log2e), K[BH,T,hd],
// Vt[BH,hd,T]. Block: one (bh, 64-token tile). 256 threads.
// ---------------------------------------------------------------------------
#define Q_SCALE 0.18033688011112042f  // 1/sqrt(64) * log2(e)

__global__ __launch_bounds__(256) void reorder_qkv(
    const u16* __restrict__ qkv, u16* __restrict__ Q, u16* __restrict__ Kb,
    u16* __restrict__ Vt) {
  const int bh = blockIdx.y, tb = blockIdx.x;
  const int b = bh >> 4, h = bh & 15;
  const size_t row0 = (size_t)b * T_SEQ + tb * 64;  // qkv row base
  __shared__ u16 vt[64][68];
  const int tid = threadIdx.x;
#pragma unroll
  for (int i = 0; i < 4; ++i) {
    const int e = tid + i * 256;
    const int row = e >> 4, c4 = (e & 15) * 4;
    const u16* src = qkv + (row0 + row) * (3 * C_EMBD) + h * HEAD_D;
    ushort4 qv = *(const ushort4*)(src + c4);
    ushort4 qo;
    qo.x = f2b(b2f(qv.x) * Q_SCALE);
    qo.y = f2b(b2f(qv.y) * Q_SCALE);
    qo.z = f2b(b2f(qv.z) * Q_SCALE);
    qo.w = f2b(b2f(qv.w) * Q_SCALE);
    const size_t dst = ((size_t)bh * T_SEQ + tb * 64 + row) * HEAD_D + c4;
    *(ushort4*)(Q + dst) = qo;
    *(ushort4*)(Kb + dst) = *(const ushort4*)(src + C_EMBD + c4);
    ushort4 vv = *(const ushort4*)(src + 2 * C_EMBD + c4);
    vt[row][c4] = vv.x; vt[row][c4 + 1] = vv.y;
    vt[row][c4 + 2] = vv.z; vt[row][c4 + 3] = vv.w;
  }
  __syncthreads();
#pragma unroll
  for (int i = 0; i < 4; ++i) {
    const int e = tid + i * 256;
    const int d = e >> 4, t4 = (e & 15) * 4;
    ushort4 ov;
    ov.x = vt[t4][d]; ov.y = vt[t4 + 1][d];
    ov.z = vt[t4 + 2][d]; ov.w = vt[t4 + 3][d];
    *(ushort4*)(Vt + ((size_t)bh * HEAD_D + d) * T_SEQ + tb * 64 + t4) = ov;
  }
}

// ---------------------------------------------------------------------------
// Flash attention (causal), LDS-staged double-buffered K/V, triangle-paired.
// TRANSPOSED inner math: S^T = mfma(K,Q) puts q = lane&15 -> softmax state is
// per-lane scalar; reductions = reg tree + shfl_xor(16,32). O^T = mfma(V^T,P^T)
// keeps rescale in-lane. Fragment reads identical to the untransposed form.
// ---------------------------------------------------------------------------
__global__ __launch_bounds__(256) void attn_fwd(
    const u16* __restrict__ Q, const u16* __restrict__ Kb,
    const u16* __restrict__ Vt, u16* __restrict__ Y) {
  const int bh = blockIdx.y;
  const int pair = blockIdx.x;
  const int nqt = (int)(T_SEQ / 64);
  const int tid = threadIdx.x;
  const int wave = tid >> 6, lane = tid & 63;
  const int quad = lane >> 4, l16 = lane & 15;
  const int sw = l16 & 7;  // xor-swizzle key for frag reads
  const u16* Qp = Q + (size_t)bh * T_SEQ * HEAD_D;
  const u16* Kp = Kb + (size_t)bh * T_SEQ * HEAD_D;
  const u16* Vp = Vt + (size_t)bh * HEAD_D * T_SEQ;

  __shared__ u16 Ks[2][64 * 64];
  __shared__ u16 Vs[2][64 * 64];
  __shared__ u16 Pl[4][16 * 72];

  auto stage = [&](u16* dst, const u16* srcBase, size_t stride) {
#pragma unroll
    for (int i = 0; i < 2; ++i) {
      const int c = tid + i * 256;
      const int row = c >> 3;
      const int gc = (c & 7) ^ (row & 7);
      load_lds16(srcBase + (size_t)row * stride + gc * 8, dst + c * 8);
    }
  };

  const int b = bh >> 4, h = bh & 15;

#pragma unroll 1
  for (int phase = 0; phase < 2; ++phase) {
    const int qb = phase == 0 ? (nqt - 1 - pair) : pair;
    const int q0 = qb * 64;
    const int qglob = q0 + wave * 16 + l16;  // this lane's q row

    if (phase == 1) __syncthreads();  // protect Ks/Vs from prior readers

    bf16x8 qF[2];
    qF[0] = *(const bf16x8*)&Qp[(size_t)qglob * HEAD_D + quad * 8];
    qF[1] = *(const bf16x8*)&Qp[(size_t)qglob * HEAD_D + 32 + quad * 8];

    f32x4 o[4] = {};   // O^T: d = nt*16 + quad*4 + r, q = l16
    float mrun = -3e38f, lrun = 0.0f;

    stage(Ks[0], Kp, HEAD_D);
    stage(Vs[0], Vp, T_SEQ);

    int buf = 0;
    for (int kb = 0; kb <= qb; ++kb) {
      const int k0 = kb * 64;
      __syncthreads();  // drains DMA + all waves' prior-buffer reads
      if (kb < qb) {
        const int k1 = k0 + 64;
        stage(Ks[buf ^ 1], Kp + (size_t)k1 * HEAD_D, HEAD_D);
        stage(Vs[buf ^ 1], Vp + k1, T_SEQ);
      }
      // S^T: key = nt*16 + quad*4 + r (rows), q = l16 (cols)
      f32x4 st[4] = {};
#pragma unroll
      for (int ks = 0; ks < 2; ++ks) {
#pragma unroll
        for (int nt = 0; nt < 4; ++nt) {
          bf16x8 kF = *(const bf16x8*)
              &Ks[buf][(nt * 16 + l16) * 64 + (((ks * 4 + quad) ^ sw) * 8)];
          st[nt] = __builtin_amdgcn_mfma_f32_16x16x32_bf16(kF, qF[ks], st[nt],
                                                           0, 0, 0);
        }
      }
      if (kb == qb) {  // causal mask, diagonal tile only
#pragma unroll
        for (int nt = 0; nt < 4; ++nt) {
#pragma unroll
          for (int r = 0; r < 4; ++r) {
            const int key = k0 + nt * 16 + quad * 4 + r;
            if (key > qglob) st[nt][r] = -3e38f;
          }
        }
      }
      // online softmax over keys: register tree + cross-quad (lanes ^16,^32)
      float m = st[0][0];
#pragma unroll
      for (int nt = 0; nt < 4; ++nt)
#pragma unroll
        for (int r = 0; r < 4; ++r) m = fmaxf(m, st[nt][r]);
      m = fmaxf(m, __shfl_xor(m, 16, 64));
      m = fmaxf(m, __shfl_xor(m, 32, 64));
      const float nm = fmaxf(mrun, m);
      const float alpha = __builtin_amdgcn_exp2f(mrun - nm);
      mrun = nm;
      float sum = 0.0f;
#pragma unroll
      for (int nt = 0; nt < 4; ++nt)
#pragma unroll
        for (int r = 0; r < 4; ++r) {
          const float p = __builtin_amdgcn_exp2f(st[nt][r] - nm);
          st[nt][r] = p;
          sum += p;
        }
      sum += __shfl_xor(sum, 16, 64);
      sum += __shfl_xor(sum, 32, 64);
      lrun = lrun * alpha + sum;
#pragma unroll
      for (int nt = 0; nt < 4; ++nt)
#pragma unroll
        for (int r = 0; r < 4; ++r) o[nt][r] *= alpha;
      // P^T -> LDS: row = q (l16), col = key; packed ushort4 per nt
#pragma unroll
      for (int nt = 0; nt < 4; ++nt) {
        ushort4 pk;
        pk.x = f2b(st[nt][0]); pk.y = f2b(st[nt][1]);
        pk.z = f2b(st[nt][2]); pk.w = f2b(st[nt][3]);
        *(ushort4*)&Pl[wave][l16 * 72 + nt * 16 + quad * 4] = pk;
      }
      // O^T += V^T P^T  (A = V^T from Vs, B = P^T from Pl)
#pragma unroll
      for (int ks = 0; ks < 2; ++ks) {
        bf16x8 aP = *(const bf16x8*)&Pl[wave][l16 * 72 + ks * 32 + quad * 8];
#pragma unroll
        for (int nt = 0; nt < 4; ++nt) {
          bf16x8 vF = *(const bf16x8*)
              &Vs[buf][(nt * 16 + l16) * 64 + (((ks * 4 + quad) ^ sw) * 8)];
          o[nt] =
              __builtin_amdgcn_mfma_f32_16x16x32_bf16(vF, aP, o[nt], 0, 0, 0);
        }
      }
      buf ^= 1;
    }

    // write O^T / l -> Y bf16 [B,T,C]: row = token (l16), cols = d
    const float rl = 1.0f / lrun;
    u16* yp = Y + ((size_t)(b * T_SEQ + qglob)) * C_EMBD + h * HEAD_D;
#pragma unroll
    for (int nt = 0; nt < 4; ++nt) {
      ushort4 ov;
      ov.x = f2b(o[nt][0] * rl); ov.y = f2b(o[nt][1] * rl);
      ov.z = f2b(o[nt][2] * rl); ov.w = f2b(o[nt][3] * rl);
      *(ushort4*)&yp[nt * 16 + quad * 4] = ov;
    }
  }
}

// ---------------------------------------------------------------------------
// Host side
// ---------------------------------------------------------------------------
extern "C" void kernel_launch(void* const* d_in, const int* in_sizes, int n_in,
                              void* d_out, int out_size, void* d_ws,
                              size_t ws_size, hipStream_t stream) {
  const float* x      = (const float*)d_in[0];
  const float* W_attn = (const float*)d_in[1];
  const float* b_attn = (const float*)d_in[2];
  const float* W_proj = (const float*)d_in[3];
  const float* b_proj = (const float*)d_in[4];
  const float* W_fc   = (const float*)d_in[5];
  const float* b_fc   = (const float*)d_in[6];
  const float* W_fc2  = (const float*)d_in[7];
  const float* b_fc2  = (const float*)d_in[8];
  const float* ln1_g  = (const float*)d_in[9];
  const float* ln1_b  = (const float*)d_in[10];
  const float* ln2_g  = (const float*)d_in[11];
  const float* ln2_b  = (const float*)d_in[12];

  u16* wqkvT = (u16*)d_ws;                            // [3072][1024] bf16
  u16* wprojT = wqkvT + (size_t)3072 * 1024;          // [1024][1024]
  u16* wfcT  = wprojT + (size_t)1024 * 1024;          // [4096][1024]
  u16* wfc2T = wfcT + (size_t)4096 * 1024;            // [1024][4096]
  u16* Abuf  = wfc2T + (size_t)1024 * 4096;           // [4096][1024] bf16
  float* x1  = (float*)(Abuf + (size_t)M_TOK * C_EMBD);  // [4096][1024] f32
  u16* hbuf  = (u16*)(x1 + (size_t)M_TOK * C_EMBD);   // [4096][4096] bf16, 32MB
  u16* qkvb  = hbuf;                                  // [4096][3072] (dead before h)
  float* projP = (float*)hbuf;                        // proj partials 2x16MB (dead window)
  u16* Qb    = hbuf + (size_t)M_TOK * 4096;           // [32][2048][64]
  u16* Kbuf  = Qb + (size_t)32 * T_SEQ * HEAD_D;
  u16* Vtb   = Kbuf + (size_t)32 * T_SEQ * HEAD_D;
  float* fc2P1 = (float*)Qb;                          // fc2 partial z=1 (16MB, dead)

  const dim3 blk(256);

  transpose_cast<<<dim3(3072 / 32, 1024 / 32), blk, 0, stream>>>(W_attn, wqkvT, 1024, 3072);
  transpose_cast<<<dim3(1024 / 32, 1024 / 32), blk, 0, stream>>>(W_proj, wprojT, 1024, 1024);
  transpose_cast<<<dim3(4096 / 32, 1024 / 32), blk, 0, stream>>>(W_fc, wfcT, 1024, 4096);
  transpose_cast<<<dim3(1024 / 32, 4096 / 32), blk, 0, stream>>>(W_fc2, wfc2T, 4096, 1024);

  ln_cast<<<M_TOK, blk, 0, stream>>>(x, ln1_g, ln1_b, Abuf);

  gemm_bt<EPI_BF16, 4, 1><<<dim3(3072 / 128, M_TOK / 128), blk, 0, stream>>>(
      Abuf, wqkvT, b_attn, nullptr, qkvb, nullptr, M_TOK, 3072, 1024);

  reorder_qkv<<<dim3(T_SEQ / 64, 32), blk, 0, stream>>>(qkvb, Qb, Kbuf, Vtb);

  attn_fwd<<<dim3(T_SEQ / 128, 32), blk, 0, stream>>>(Qb, Kbuf, Vtb, Abuf);

  // proj: split-K=2 partials into hbuf region, then reduce (+bias+x) -> x1
  gemm_bt<EPI_PART, 4, 2><<<dim3(1024 / 128, M_TOK / 128, 2), blk, 0, stream>>>(
      Abuf, wprojT, nullptr, nullptr, projP, projP + (size_t)M_TOK * C_EMBD,
      M_TOK, 1024, 1024);
  reduce_add<<<M_TOK * C_EMBD / 1024, blk, 0, stream>>>(
      projP, projP + (size_t)M_TOK * C_EMBD, b_proj, x, x1);

  ln_cast<<<M_TOK, blk, 0, stream>>>(x1, ln2_g, ln2_b, Abuf);

  gemm_bt<EPI_GELU_BF16, 4, 1><<<dim3(4096 / 128, M_TOK / 128), blk, 0, stream>>>(
      Abuf, wfcT, b_fc, nullptr, hbuf, nullptr, M_TOK, 4096, 1024);

  // fc2: split-K=2, partial z=0 -> d_out, z=1 -> dead Q/K region, reduce in place
  gemm_bt<EPI_PART, 4, 2><<<dim3(1024 / 128, M_TOK / 128, 2), blk, 0, stream>>>(
      hbuf, wfc2T, nullptr, nullptr, d_out, fc2P1, M_TOK, 1024, 4096);
  reduce_add<<<M_TOK * C_EMBD / 1024, blk, 0, stream>>>(
      (const float*)d_out, fc2P1, b_fc2, x1, (float*)d_out);
}

// Round 5
// 375.350 us; speedup vs baseline: 1.6301x; 1.1192x over previous
//
#include <hip/hip_runtime.h>
#include <cstdint>
#include <cstddef>

// ---------------------------------------------------------------------------
// Transformer block on MI355X (gfx950), bf16 MFMA path.
// R5: GEMM rebuilt — BK=64, xor-swizzled LDS (conflict-free frag reads),
//     32 MFMA/barrier, TRANSPOSED accumulation (C^T via mfma(B,A)) giving
//     packed ushort4/float4 epilogue stores, exp2-based tanh GELU.
// ---------------------------------------------------------------------------

typedef unsigned short u16;
typedef short bf16x8 __attribute__((ext_vector_type(8)));
typedef float f32x4 __attribute__((ext_vector_type(4)));

#define C_EMBD 1024
#define T_SEQ  2048
#define N_BATCH 2
#define N_HEADS 16
#define HEAD_D 64
#define M_TOK  4096   // N_BATCH * T_SEQ

__device__ __forceinline__ u16 f2b(float f) {
  union { float f; unsigned u; } v; v.f = f;
  unsigned r = (v.u + 0x7fffu + ((v.u >> 16) & 1u)) >> 16;  // RNE
  return (u16)r;
}
__device__ __forceinline__ float b2f(u16 u) {
  union { unsigned u; float f; } v; v.u = ((unsigned)u) << 16;
  return v.f;
}
__device__ __forceinline__ void load_lds16(const void* g, void* l) {
  __builtin_amdgcn_global_load_lds(
      (const __attribute__((address_space(1))) void*)g,
      (__attribute__((address_space(3))) void*)l, 16, 0, 0);
}
// tanh-form GELU in exp2 domain: x * t/(t+1), t = exp2(2.3021859*(x+0.044715x^3))
__device__ __forceinline__ float gelu_fast(float x) {
  const float p = x * __builtin_fmaf(0.044715f * x, x, 1.0f);
  const float t = __builtin_amdgcn_exp2f(2.3021859215f * p);
  return x * t * __builtin_amdgcn_rcpf(t + 1.0f);
}

// ---------------------------------------------------------------------------
// Weight transpose + cast: W[K][N] fp32 -> Wt[N][K] bf16
// ---------------------------------------------------------------------------
__global__ __launch_bounds__(256) void transpose_cast(
    const float* __restrict__ W, u16* __restrict__ Wt, int K, int N) {
  __shared__ float tile[32][33];
  const int n0 = blockIdx.x * 32, k0 = blockIdx.y * 32;
  const int tx = threadIdx.x & 31, ty = threadIdx.x >> 5;  // ty in [0,8)
#pragma unroll
  for (int i = 0; i < 32; i += 8)
    tile[ty + i][tx] = W[(size_t)(k0 + ty + i) * N + n0 + tx];
  __syncthreads();
#pragma unroll
  for (int i = 0; i < 32; i += 8)
    Wt[(size_t)(n0 + ty + i) * K + k0 + tx] = f2b(tile[tx][ty + i]);
}

// ---------------------------------------------------------------------------
// LayerNorm over rows of 1024 fp32 -> bf16 out. One block (256 thr) per row.
// ---------------------------------------------------------------------------
__global__ __launch_bounds__(256) void ln_cast(
    const float* __restrict__ X, const float* __restrict__ g,
    const float* __restrict__ b, u16* __restrict__ Y) {
  const int row = blockIdx.x;
  const int tid = threadIdx.x;
  const float4 v = ((const float4*)(X + (size_t)row * C_EMBD))[tid];
  float s = v.x + v.y + v.z + v.w;
  float ss = v.x * v.x + v.y * v.y + v.z * v.z + v.w * v.w;
#pragma unroll
  for (int off = 32; off > 0; off >>= 1) {
    s += __shfl_down(s, off, 64);
    ss += __shfl_down(ss, off, 64);
  }
  __shared__ float red[8];
  __shared__ float stats[2];
  const int wave = tid >> 6, lane = tid & 63;
  if (lane == 0) { red[wave] = s; red[4 + wave] = ss; }
  __syncthreads();
  if (tid == 0) {
    float S = red[0] + red[1] + red[2] + red[3];
    float SS = red[4] + red[5] + red[6] + red[7];
    float mu = S * (1.0f / C_EMBD);
    float var = SS * (1.0f / C_EMBD) - mu * mu;
    stats[0] = mu;
    stats[1] = rsqrtf(var + 1e-5f);
  }
  __syncthreads();
  const float mu = stats[0], rs = stats[1];
  const float4 gv = ((const float4*)g)[tid];
  const float4 bv = ((const float4*)b)[tid];
  ushort4 o;
  o.x = f2b((v.x - mu) * rs * gv.x + bv.x);
  o.y = f2b((v.y - mu) * rs * gv.y + bv.y);
  o.z = f2b((v.z - mu) * rs * gv.z + bv.z);
  o.w = f2b((v.w - mu) * rs * gv.w + bv.w);
  ((ushort4*)(Y + (size_t)row * C_EMBD))[tid] = o;
}

// ---------------------------------------------------------------------------
// GEMM: C[M,N] = A[M,K](bf16) * Bt[N,K](bf16)^T (+bias/gelu). BK=64,
// xor-swizzled LDS, transposed acc (C^T): lane holds row m=..+l16, 4
// consecutive cols per reg -> packed stores. 128x128 tile, 4 waves (2x2).
// SPLIT=2: blockIdx.z selects K-half, raw f32 partials to Cout/Cout2.
// ---------------------------------------------------------------------------
enum { EPI_BF16 = 0, EPI_GELU_BF16 = 2, EPI_PART = 3 };

template <int EPI, int SPLIT>
__global__ __launch_bounds__(256) void gemm_bt(
    const u16* __restrict__ A, const u16* __restrict__ Bt,
    const float* __restrict__ bias,
    void* __restrict__ Cout, void* __restrict__ Cout2, int M, int N, int K) {
  __shared__ u16 As[128 * 64];
  __shared__ u16 Bs[128 * 64];
  const int tid = threadIdx.x;
  const int wave = tid >> 6, lane = tid & 63;
  const int quad = lane >> 4, l16 = lane & 15;
  const int sw = l16 & 7;
  const int m0 = blockIdx.y * 128, n0 = blockIdx.x * 128;
  const int wm = (wave >> 1) * 64, wn = (wave & 1) * 64;

  f32x4 acc[4][4] = {};  // acc[tm][tn][r]: m = wm+tm*16+l16, n = wn+tn*16+quad*4+r

  const int kTiles = (K >> 6) / SPLIT;
  const int kt0 = (SPLIT == 2) ? (int)blockIdx.z * kTiles : 0;
  for (int kt = kt0; kt < kt0 + kTiles; ++kt) {
    const int k0 = kt << 6;
    // stage 128x64: 1024 chunks each, 4/thread; col8 xor-swizzled by row&7
#pragma unroll
    for (int i = 0; i < 4; ++i) {
      const int c = tid + i * 256;
      const int row = c >> 3, gc = ((c & 7) ^ (row & 7)) * 8;
      load_lds16(A + (size_t)(m0 + row) * K + k0 + gc, &As[c * 8]);
    }
#pragma unroll
    for (int i = 0; i < 4; ++i) {
      const int c = tid + i * 256;
      const int row = c >> 3, gc = ((c & 7) ^ (row & 7)) * 8;
      load_lds16(Bt + (size_t)(n0 + row) * K + k0 + gc, &Bs[c * 8]);
    }
    __syncthreads();
#pragma unroll
    for (int ks = 0; ks < 2; ++ks) {
      bf16x8 aF[4], bF[4];
#pragma unroll
      for (int t = 0; t < 4; ++t) {
        aF[t] = *(const bf16x8*)
            &As[(wm + t * 16 + l16) * 64 + (((ks * 4 + quad) ^ sw) * 8)];
        bF[t] = *(const bf16x8*)
            &Bs[(wn + t * 16 + l16) * 64 + (((ks * 4 + quad) ^ sw) * 8)];
      }
#pragma unroll
      for (int tm = 0; tm < 4; ++tm)
#pragma unroll
        for (int tn = 0; tn < 4; ++tn)
          acc[tm][tn] = __builtin_amdgcn_mfma_f32_16x16x32_bf16(
              bF[tn], aF[tm], acc[tm][tn], 0, 0, 0);  // transposed: C^T
    }
    __syncthreads();
  }

  float* Pz = (float*)((SPLIT == 2 && blockIdx.z == 1) ? Cout2 : Cout);
#pragma unroll
  for (int tm = 0; tm < 4; ++tm) {
    const int row = m0 + wm + tm * 16 + l16;
#pragma unroll
    for (int tn = 0; tn < 4; ++tn) {
      const int col = n0 + wn + tn * 16 + quad * 4;
      if constexpr (EPI == EPI_PART) {
        *(float4*)&Pz[(size_t)row * N + col] = *(float4*)&acc[tm][tn];
      } else {
        const float4 bz = *(const float4*)&bias[col];
        float v0 = acc[tm][tn][0] + bz.x, v1 = acc[tm][tn][1] + bz.y;
        float v2 = acc[tm][tn][2] + bz.z, v3 = acc[tm][tn][3] + bz.w;
        if constexpr (EPI == EPI_GELU_BF16) {
          v0 = gelu_fast(v0); v1 = gelu_fast(v1);
          v2 = gelu_fast(v2); v3 = gelu_fast(v3);
        }
        ushort4 o;
        o.x = f2b(v0); o.y = f2b(v1); o.z = f2b(v2); o.w = f2b(v3);
        *(ushort4*)&((u16*)Cout)[(size_t)row * N + col] = o;
      }
    }
  }
}

// ---------------------------------------------------------------------------
// reduce: out = P0 + P1 + bias[col] + res. N fixed 1024. float4 per thread.
// ---------------------------------------------------------------------------
__global__ __launch_bounds__(256) void reduce_add(
    const float* __restrict__ P0, const float* __restrict__ P1,
    const float* __restrict__ bias, const float* __restrict__ res,
    float* __restrict__ out) {
  const int idx = blockIdx.x * 256 + threadIdx.x;  // float4 index
  const float4 a = ((const float4*)P0)[idx];
  const float4 b = ((const float4*)P1)[idx];
  const float4 c = ((const float4*)res)[idx];
  const float4 g = ((const float4*)bias)[idx & 255];  // 1024/4 = 256
  float4 o;
  o.x = a.x + b.x + c.x + g.x;
  o.y = a.y + b.y + c.y + g.y;
  o.z = a.z + b.z + c.z + g.z;
  o.w = a.w + b.w + c.w + g.w;
  ((float4*)out)[idx] = o;
}

// ---------------------------------------------------------------------------
// Reorder qkv[M,3C] bf16 -> Q[BH,T,hd] (scaled 0.125*log2e), K[BH,T,hd],
// Vt[BH,hd,T]. Block: one (bh, 64-token tile). 256 threads.
// ---------------------------------------------------------------------------
#define Q_SCALE 0.18033688011112042f  // 1/sqrt(64) * log2(e)

__global__ __launch_bounds__(256) void reorder_qkv(
    const u16* __restrict__ qkv, u16* __restrict__ Q, u16* __restrict__ Kb,
    u16* __restrict__ Vt) {
  const int bh = blockIdx.y, tb = blockIdx.x;
  const int b = bh >> 4, h = bh & 15;
  const size_t row0 = (size_t)b * T_SEQ + tb * 64;  // qkv row base
  __shared__ u16 vt[64][68];
  const int tid = threadIdx.x;
#pragma unroll
  for (int i = 0; i < 4; ++i) {
    const int e = tid + i * 256;
    const int row = e >> 4, c4 = (e & 15) * 4;
    const u16* src = qkv + (row0 + row) * (3 * C_EMBD) + h * HEAD_D;
    ushort4 qv = *(const ushort4*)(src + c4);
    ushort4 qo;
    qo.x = f2b(b2f(qv.x) * Q_SCALE);
    qo.y = f2b(b2f(qv.y) * Q_SCALE);
    qo.z = f2b(b2f(qv.z) * Q_SCALE);
    qo.w = f2b(b2f(qv.w) * Q_SCALE);
    const size_t dst = ((size_t)bh * T_SEQ + tb * 64 + row) * HEAD_D + c4;
    *(ushort4*)(Q + dst) = qo;
    *(ushort4*)(Kb + dst) = *(const ushort4*)(src + C_EMBD + c4);
    ushort4 vv = *(const ushort4*)(src + 2 * C_EMBD + c4);
    vt[row][c4] = vv.x; vt[row][c4 + 1] = vv.y;
    vt[row][c4 + 2] = vv.z; vt[row][c4 + 3] = vv.w;
  }
  __syncthreads();
#pragma unroll
  for (int i = 0; i < 4; ++i) {
    const int e = tid + i * 256;
    const int d = e >> 4, t4 = (e & 15) * 4;
    ushort4 ov;
    ov.x = vt[t4][d]; ov.y = vt[t4 + 1][d];
    ov.z = vt[t4 + 2][d]; ov.w = vt[t4 + 3][d];
    *(ushort4*)(Vt + ((size_t)bh * HEAD_D + d) * T_SEQ + tb * 64 + t4) = ov;
  }
}

// ---------------------------------------------------------------------------
// Flash attention (causal), LDS-staged double-buffered K/V, triangle-paired.
// Transposed math: S^T = mfma(K,Q) -> per-lane scalar softmax state,
// O^T = mfma(V^T,P^T) -> in-lane rescale, packed O writes.
// ---------------------------------------------------------------------------
__global__ __launch_bounds__(256) void attn_fwd(
    const u16* __restrict__ Q, const u16* __restrict__ Kb,
    const u16* __restrict__ Vt, u16* __restrict__ Y) {
  const int bh = blockIdx.y;
  const int pair = blockIdx.x;
  const int nqt = (int)(T_SEQ / 64);
  const int tid = threadIdx.x;
  const int wave = tid >> 6, lane = tid & 63;
  const int quad = lane >> 4, l16 = lane & 15;
  const int sw = l16 & 7;  // xor-swizzle key for frag reads
  const u16* Qp = Q + (size_t)bh * T_SEQ * HEAD_D;
  const u16* Kp = Kb + (size_t)bh * T_SEQ * HEAD_D;
  const u16* Vp = Vt + (size_t)bh * HEAD_D * T_SEQ;

  __shared__ u16 Ks[2][64 * 64];
  __shared__ u16 Vs[2][64 * 64];
  __shared__ u16 Pl[4][16 * 72];

  auto stage = [&](u16* dst, const u16* srcBase, size_t stride) {
#pragma unroll
    for (int i = 0; i < 2; ++i) {
      const int c = tid + i * 256;
      const int row = c >> 3;
      const int gc = (c & 7) ^ (row & 7);
      load_lds16(srcBase + (size_t)row * stride + gc * 8, dst + c * 8);
    }
  };

  const int b = bh >> 4, h = bh & 15;

#pragma unroll 1
  for (int phase = 0; phase < 2; ++phase) {
    const int qb = phase == 0 ? (nqt - 1 - pair) : pair;
    const int q0 = qb * 64;
    const int qglob = q0 + wave * 16 + l16;  // this lane's q row

    if (phase == 1) __syncthreads();  // protect Ks/Vs from prior readers

    bf16x8 qF[2];
    qF[0] = *(const bf16x8*)&Qp[(size_t)qglob * HEAD_D + quad * 8];
    qF[1] = *(const bf16x8*)&Qp[(size_t)qglob * HEAD_D + 32 + quad * 8];

    f32x4 o[4] = {};   // O^T: d = nt*16 + quad*4 + r, q = l16
    float mrun = -3e38f, lrun = 0.0f;

    stage(Ks[0], Kp, HEAD_D);
    stage(Vs[0], Vp, T_SEQ);

    int buf = 0;
    for (int kb = 0; kb <= qb; ++kb) {
      const int k0 = kb * 64;
      __syncthreads();  // drains DMA + all waves' prior-buffer reads
      if (kb < qb) {
        const int k1 = k0 + 64;
        stage(Ks[buf ^ 1], Kp + (size_t)k1 * HEAD_D, HEAD_D);
        stage(Vs[buf ^ 1], Vp + k1, T_SEQ);
      }
      // S^T: key = nt*16 + quad*4 + r (rows), q = l16 (cols)
      f32x4 st[4] = {};
#pragma unroll
      for (int ks = 0; ks < 2; ++ks) {
#pragma unroll
        for (int nt = 0; nt < 4; ++nt) {
          bf16x8 kF = *(const bf16x8*)
              &Ks[buf][(nt * 16 + l16) * 64 + (((ks * 4 + quad) ^ sw) * 8)];
          st[nt] = __builtin_amdgcn_mfma_f32_16x16x32_bf16(kF, qF[ks], st[nt],
                                                           0, 0, 0);
        }
      }
      if (kb == qb) {  // causal mask, diagonal tile only
#pragma unroll
        for (int nt = 0; nt < 4; ++nt) {
#pragma unroll
          for (int r = 0; r < 4; ++r) {
            const int key = k0 + nt * 16 + quad * 4 + r;
            if (key > qglob) st[nt][r] = -3e38f;
          }
        }
      }
      // online softmax over keys: register tree + cross-quad (lanes ^16,^32)
      float m = st[0][0];
#pragma unroll
      for (int nt = 0; nt < 4; ++nt)
#pragma unroll
        for (int r = 0; r < 4; ++r) m = fmaxf(m, st[nt][r]);
      m = fmaxf(m, __shfl_xor(m, 16, 64));
      m = fmaxf(m, __shfl_xor(m, 32, 64));
      const float nm = fmaxf(mrun, m);
      const float alpha = __builtin_amdgcn_exp2f(mrun - nm);
      mrun = nm;
      float sum = 0.0f;
#pragma unroll
      for (int nt = 0; nt < 4; ++nt)
#pragma unroll
        for (int r = 0; r < 4; ++r) {
          const float p = __builtin_amdgcn_exp2f(st[nt][r] - nm);
          st[nt][r] = p;
          sum += p;
        }
      sum += __shfl_xor(sum, 16, 64);
      sum += __shfl_xor(sum, 32, 64);
      lrun = lrun * alpha + sum;
#pragma unroll
      for (int nt = 0; nt < 4; ++nt)
#pragma unroll
        for (int r = 0; r < 4; ++r) o[nt][r] *= alpha;
      // P^T -> LDS: row = q (l16), col = key; packed ushort4 per nt
#pragma unroll
      for (int nt = 0; nt < 4; ++nt) {
        ushort4 pk;
        pk.x = f2b(st[nt][0]); pk.y = f2b(st[nt][1]);
        pk.z = f2b(st[nt][2]); pk.w = f2b(st[nt][3]);
        *(ushort4*)&Pl[wave][l16 * 72 + nt * 16 + quad * 4] = pk;
      }
      // O^T += V^T P^T  (A = V^T from Vs, B = P^T from Pl)
#pragma unroll
      for (int ks = 0; ks < 2; ++ks) {
        bf16x8 aP = *(const bf16x8*)&Pl[wave][l16 * 72 + ks * 32 + quad * 8];
#pragma unroll
        for (int nt = 0; nt < 4; ++nt) {
          bf16x8 vF = *(const bf16x8*)
              &Vs[buf][(nt * 16 + l16) * 64 + (((ks * 4 + quad) ^ sw) * 8)];
          o[nt] =
              __builtin_amdgcn_mfma_f32_16x16x32_bf16(vF, aP, o[nt], 0, 0, 0);
        }
      }
      buf ^= 1;
    }

    // write O^T / l -> Y bf16 [B,T,C]: row = token (l16), cols = d
    const float rl = 1.0f / lrun;
    u16* yp = Y + ((size_t)(b * T_SEQ + qglob)) * C_EMBD + h * HEAD_D;
#pragma unroll
    for (int nt = 0; nt < 4; ++nt) {
      ushort4 ov;
      ov.x = f2b(o[nt][0] * rl); ov.y = f2b(o[nt][1] * rl);
      ov.z = f2b(o[nt][2] * rl); ov.w = f2b(o[nt][3] * rl);
      *(ushort4*)&yp[nt * 16 + quad * 4] = ov;
    }
  }
}

// ---------------------------------------------------------------------------
// Host side
// ---------------------------------------------------------------------------
extern "C" void kernel_launch(void* const* d_in, const int* in_sizes, int n_in,
                              void* d_out, int out_size, void* d_ws,
                              size_t ws_size, hipStream_t stream) {
  const float* x      = (const float*)d_in[0];
  const float* W_attn = (const float*)d_in[1];
  const float* b_attn = (const float*)d_in[2];
  const float* W_proj = (const float*)d_in[3];
  const float* b_proj = (const float*)d_in[4];
  const float* W_fc   = (const float*)d_in[5];
  const float* b_fc   = (const float*)d_in[6];
  const float* W_fc2  = (const float*)d_in[7];
  const float* b_fc2  = (const float*)d_in[8];
  const float* ln1_g  = (const float*)d_in[9];
  const float* ln1_b  = (const float*)d_in[10];
  const float* ln2_g  = (const float*)d_in[11];
  const float* ln2_b  = (const float*)d_in[12];

  u16* wqkvT = (u16*)d_ws;                            // [3072][1024] bf16
  u16* wprojT = wqkvT + (size_t)3072 * 1024;          // [1024][1024]
  u16* wfcT  = wprojT + (size_t)1024 * 1024;          // [4096][1024]
  u16* wfc2T = wfcT + (size_t)4096 * 1024;            // [1024][4096]
  u16* Abuf  = wfc2T + (size_t)1024 * 4096;           // [4096][1024] bf16
  float* x1  = (float*)(Abuf + (size_t)M_TOK * C_EMBD);  // [4096][1024] f32
  u16* hbuf  = (u16*)(x1 + (size_t)M_TOK * C_EMBD);   // [4096][4096] bf16, 32MB
  u16* qkvb  = hbuf;                                  // [4096][3072] (dead before h)
  float* projP = (float*)hbuf;                        // proj partials 2x16MB (dead window)
  u16* Qb    = hbuf + (size_t)M_TOK * 4096;           // [32][2048][64]
  u16* Kbuf  = Qb + (size_t)32 * T_SEQ * HEAD_D;
  u16* Vtb   = Kbuf + (size_t)32 * T_SEQ * HEAD_D;
  float* fc2P1 = (float*)Qb;                          // fc2 partial z=1 (16MB, dead)

  const dim3 blk(256);

  transpose_cast<<<dim3(3072 / 32, 1024 / 32), blk, 0, stream>>>(W_attn, wqkvT, 1024, 3072);
  transpose_cast<<<dim3(1024 / 32, 1024 / 32), blk, 0, stream>>>(W_proj, wprojT, 1024, 1024);
  transpose_cast<<<dim3(4096 / 32, 1024 / 32), blk, 0, stream>>>(W_fc, wfcT, 1024, 4096);
  transpose_cast<<<dim3(1024 / 32, 4096 / 32), blk, 0, stream>>>(W_fc2, wfc2T, 4096, 1024);

  ln_cast<<<M_TOK, blk, 0, stream>>>(x, ln1_g, ln1_b, Abuf);

  gemm_bt<EPI_BF16, 1><<<dim3(3072 / 128, M_TOK / 128), blk, 0, stream>>>(
      Abuf, wqkvT, b_attn, qkvb, nullptr, M_TOK, 3072, 1024);

  reorder_qkv<<<dim3(T_SEQ / 64, 32), blk, 0, stream>>>(qkvb, Qb, Kbuf, Vtb);

  attn_fwd<<<dim3(T_SEQ / 128, 32), blk, 0, stream>>>(Qb, Kbuf, Vtb, Abuf);

  // proj: split-K=2 partials into hbuf region, then reduce (+bias+x) -> x1
  gemm_bt<EPI_PART, 2><<<dim3(1024 / 128, M_TOK / 128, 2), blk, 0, stream>>>(
      Abuf, wprojT, nullptr, projP, projP + (size_t)M_TOK * C_EMBD,
      M_TOK, 1024, 1024);
  reduce_add<<<M_TOK * C_EMBD / 1024, blk, 0, stream>>>(
      projP, projP + (size_t)M_TOK * C_EMBD, b_proj, x, x1);

  ln_cast<<<M_TOK, blk, 0, stream>>>(x1, ln2_g, ln2_b, Abuf);

  gemm_bt<EPI_GELU_BF16, 1><<<dim3(4096 / 128, M_TOK / 128), blk, 0, stream>>>(
      Abuf, wfcT, b_fc, hbuf, nullptr, M_TOK, 4096, 1024);

  // fc2: split-K=2, partial z=0 -> d_out, z=1 -> dead Q/K region, reduce in place
  gemm_bt<EPI_PART, 2><<<dim3(1024 / 128, M_TOK / 128, 2), blk, 0, stream>>>(
      hbuf, wfc2T, nullptr, d_out, fc2P1, M_TOK, 1024, 4096);
  reduce_add<<<M_TOK * C_EMBD / 1024, blk, 0, stream>>>(
      (const float*)d_out, fc2P1, b_fc2, x1, (float*)d_out);
}

// Round 6
// 362.174 us; speedup vs baseline: 1.6894x; 1.0364x over previous
//
#include <hip/hip_runtime.h>
#include <cstdint>
#include <cstddef>

// ---------------------------------------------------------------------------
// Transformer block on MI355X (gfx950), bf16 MFMA path.
// R6: attention VALU diet — v_perm_b32 truncating P-pack (1 op per 2 vals),
//     loop-invariant staging addresses hoisted; reorder_qkv fused into the
//     qkv GEMM epilogue (EPI_QKV, branch wave-uniform per 16-col group).
// ---------------------------------------------------------------------------

typedef unsigned short u16;
typedef short bf16x8 __attribute__((ext_vector_type(8)));
typedef float f32x4 __attribute__((ext_vector_type(4)));

#define C_EMBD 1024
#define T_SEQ  2048
#define N_BATCH 2
#define N_HEADS 16
#define HEAD_D 64
#define M_TOK  4096   // N_BATCH * T_SEQ
#define Q_SCALE 0.18033688011112042f  // 1/sqrt(64) * log2(e)

__device__ __forceinline__ u16 f2b(float f) {
  union { float f; unsigned u; } v; v.f = f;
  unsigned r = (v.u + 0x7fffu + ((v.u >> 16) & 1u)) >> 16;  // RNE
  return (u16)r;
}
__device__ __forceinline__ float b2f(u16 u) {
  union { unsigned u; float f; } v; v.u = ((unsigned)u) << 16;
  return v.f;
}
// pack 2 fp32 -> bf16x2 by truncation: lo16 = a.hi16, hi16 = b.hi16 (1 VALU op)
__device__ __forceinline__ unsigned pk2(float a, float b) {
  union { float f; unsigned u; } x, y; x.f = a; y.f = b;
  return __builtin_amdgcn_perm(y.u, x.u, 0x07060302u);
}
__device__ __forceinline__ void load_lds16(const void* g, void* l) {
  __builtin_amdgcn_global_load_lds(
      (const __attribute__((address_space(1))) void*)g,
      (__attribute__((address_space(3))) void*)l, 16, 0, 0);
}
// tanh-form GELU in exp2 domain: x * t/(t+1), t = exp2(2.3021859*(x+0.044715x^3))
__device__ __forceinline__ float gelu_fast(float x) {
  const float p = x * __builtin_fmaf(0.044715f * x, x, 1.0f);
  const float t = __builtin_amdgcn_exp2f(2.3021859215f * p);
  return x * t * __builtin_amdgcn_rcpf(t + 1.0f);
}

// ---------------------------------------------------------------------------
// Weight transpose + cast: W[K][N] fp32 -> Wt[N][K] bf16
// ---------------------------------------------------------------------------
__global__ __launch_bounds__(256) void transpose_cast(
    const float* __restrict__ W, u16* __restrict__ Wt, int K, int N) {
  __shared__ float tile[32][33];
  const int n0 = blockIdx.x * 32, k0 = blockIdx.y * 32;
  const int tx = threadIdx.x & 31, ty = threadIdx.x >> 5;  // ty in [0,8)
#pragma unroll
  for (int i = 0; i < 32; i += 8)
    tile[ty + i][tx] = W[(size_t)(k0 + ty + i) * N + n0 + tx];
  __syncthreads();
#pragma unroll
  for (int i = 0; i < 32; i += 8)
    Wt[(size_t)(n0 + ty + i) * K + k0 + tx] = f2b(tile[tx][ty + i]);
}

// ---------------------------------------------------------------------------
// LayerNorm over rows of 1024 fp32 -> bf16 out. One block (256 thr) per row.
// ---------------------------------------------------------------------------
__global__ __launch_bounds__(256) void ln_cast(
    const float* __restrict__ X, const float* __restrict__ g,
    const float* __restrict__ b, u16* __restrict__ Y) {
  const int row = blockIdx.x;
  const int tid = threadIdx.x;
  const float4 v = ((const float4*)(X + (size_t)row * C_EMBD))[tid];
  float s = v.x + v.y + v.z + v.w;
  float ss = v.x * v.x + v.y * v.y + v.z * v.z + v.w * v.w;
#pragma unroll
  for (int off = 32; off > 0; off >>= 1) {
    s += __shfl_down(s, off, 64);
    ss += __shfl_down(ss, off, 64);
  }
  __shared__ float red[8];
  __shared__ float stats[2];
  const int wave = tid >> 6, lane = tid & 63;
  if (lane == 0) { red[wave] = s; red[4 + wave] = ss; }
  __syncthreads();
  if (tid == 0) {
    float S = red[0] + red[1] + red[2] + red[3];
    float SS = red[4] + red[5] + red[6] + red[7];
    float mu = S * (1.0f / C_EMBD);
    float var = SS * (1.0f / C_EMBD) - mu * mu;
    stats[0] = mu;
    stats[1] = rsqrtf(var + 1e-5f);
  }
  __syncthreads();
  const float mu = stats[0], rs = stats[1];
  const float4 gv = ((const float4*)g)[tid];
  const float4 bv = ((const float4*)b)[tid];
  ushort4 o;
  o.x = f2b((v.x - mu) * rs * gv.x + bv.x);
  o.y = f2b((v.y - mu) * rs * gv.y + bv.y);
  o.z = f2b((v.z - mu) * rs * gv.z + bv.z);
  o.w = f2b((v.w - mu) * rs * gv.w + bv.w);
  ((ushort4*)(Y + (size_t)row * C_EMBD))[tid] = o;
}

// ---------------------------------------------------------------------------
// GEMM: C[M,N] = A[M,K](bf16) * Bt[N,K](bf16)^T (+epilogue). BK=64,
// xor-swizzled LDS, transposed acc (C^T): lane holds row m=..+l16, 4
// consecutive cols per reg. 128x128 tile, 4 waves (2x2).
// EPI_QKV scatters bias-added output straight to Q (scaled) / K / V^T.
// SPLIT=2: blockIdx.z selects K-half, raw f32 partials to Cout/Cout2.
// ---------------------------------------------------------------------------
enum { EPI_BF16 = 0, EPI_GELU_BF16 = 2, EPI_PART = 3, EPI_QKV = 4 };

template <int EPI, int SPLIT>
__global__ __launch_bounds__(256) void gemm_bt(
    const u16* __restrict__ A, const u16* __restrict__ Bt,
    const float* __restrict__ bias,
    void* __restrict__ Cout, void* __restrict__ Cout2, void* __restrict__ Cout3,
    int M, int N, int K) {
  __shared__ u16 As[128 * 64];
  __shared__ u16 Bs[128 * 64];
  const int tid = threadIdx.x;
  const int wave = tid >> 6, lane = tid & 63;
  const int quad = lane >> 4, l16 = lane & 15;
  const int sw = l16 & 7;
  const int m0 = blockIdx.y * 128, n0 = blockIdx.x * 128;
  const int wm = (wave >> 1) * 64, wn = (wave & 1) * 64;

  f32x4 acc[4][4] = {};  // acc[tm][tn][r]: m = wm+tm*16+l16, n = wn+tn*16+quad*4+r

  const int kTiles = (K >> 6) / SPLIT;
  const int kt0 = (SPLIT == 2) ? (int)blockIdx.z * kTiles : 0;
  for (int kt = kt0; kt < kt0 + kTiles; ++kt) {
    const int k0 = kt << 6;
    // stage 128x64: 1024 chunks each, 4/thread; col8 xor-swizzled by row&7
#pragma unroll
    for (int i = 0; i < 4; ++i) {
      const int c = tid + i * 256;
      const int row = c >> 3, gc = ((c & 7) ^ (row & 7)) * 8;
      load_lds16(A + (size_t)(m0 + row) * K + k0 + gc, &As[c * 8]);
    }
#pragma unroll
    for (int i = 0; i < 4; ++i) {
      const int c = tid + i * 256;
      const int row = c >> 3, gc = ((c & 7) ^ (row & 7)) * 8;
      load_lds16(Bt + (size_t)(n0 + row) * K + k0 + gc, &Bs[c * 8]);
    }
    __syncthreads();
#pragma unroll
    for (int ks = 0; ks < 2; ++ks) {
      bf16x8 aF[4], bF[4];
#pragma unroll
      for (int t = 0; t < 4; ++t) {
        aF[t] = *(const bf16x8*)
            &As[(wm + t * 16 + l16) * 64 + (((ks * 4 + quad) ^ sw) * 8)];
        bF[t] = *(const bf16x8*)
            &Bs[(wn + t * 16 + l16) * 64 + (((ks * 4 + quad) ^ sw) * 8)];
      }
#pragma unroll
      for (int tm = 0; tm < 4; ++tm)
#pragma unroll
        for (int tn = 0; tn < 4; ++tn)
          acc[tm][tn] = __builtin_amdgcn_mfma_f32_16x16x32_bf16(
              bF[tn], aF[tm], acc[tm][tn], 0, 0, 0);  // transposed: C^T
    }
    __syncthreads();
  }

  float* Pz = (float*)((SPLIT == 2 && blockIdx.z == 1) ? Cout2 : Cout);
#pragma unroll
  for (int tm = 0; tm < 4; ++tm) {
    const int row = m0 + wm + tm * 16 + l16;
#pragma unroll
    for (int tn = 0; tn < 4; ++tn) {
      const int col = n0 + wn + tn * 16 + quad * 4;
      if constexpr (EPI == EPI_PART) {
        *(float4*)&Pz[(size_t)row * N + col] = *(float4*)&acc[tm][tn];
      } else if constexpr (EPI == EPI_QKV) {
        // row = token; col in [0,3072): [0,1024)=Q, [1024,2048)=K, rest=V
        const int bb = row >> 11, t = row & (T_SEQ - 1);
        const float4 bz = *(const float4*)&bias[col];
        float v0 = acc[tm][tn][0] + bz.x, v1 = acc[tm][tn][1] + bz.y;
        float v2 = acc[tm][tn][2] + bz.z, v3 = acc[tm][tn][3] + bz.w;
        const int sec = col >> 10;           // wave-uniform (16-col group)
        const int h = (col & 1023) >> 6, d4 = col & 63;
        const int bh = bb * N_HEADS + h;
        if (sec == 0) {                      // Q, pre-scaled
          ushort4 o;
          o.x = f2b(v0 * Q_SCALE); o.y = f2b(v1 * Q_SCALE);
          o.z = f2b(v2 * Q_SCALE); o.w = f2b(v3 * Q_SCALE);
          *(ushort4*)&((u16*)Cout)[((size_t)bh * T_SEQ + t) * HEAD_D + d4] = o;
        } else if (sec == 1) {               // K
          ushort4 o;
          o.x = f2b(v0); o.y = f2b(v1); o.z = f2b(v2); o.w = f2b(v3);
          *(ushort4*)&((u16*)Cout2)[((size_t)bh * T_SEQ + t) * HEAD_D + d4] = o;
        } else {                             // V^T: [bh][d][t]
          u16* vp = (u16*)Cout3 + ((size_t)bh * HEAD_D + d4) * T_SEQ + t;
          vp[0] = f2b(v0); vp[T_SEQ] = f2b(v1);
          vp[2 * T_SEQ] = f2b(v2); vp[3 * T_SEQ] = f2b(v3);
        }
      } else {
        const float4 bz = *(const float4*)&bias[col];
        float v0 = acc[tm][tn][0] + bz.x, v1 = acc[tm][tn][1] + bz.y;
        float v2 = acc[tm][tn][2] + bz.z, v3 = acc[tm][tn][3] + bz.w;
        if constexpr (EPI == EPI_GELU_BF16) {
          v0 = gelu_fast(v0); v1 = gelu_fast(v1);
          v2 = gelu_fast(v2); v3 = gelu_fast(v3);
        }
        ushort4 o;
        o.x = f2b(v0); o.y = f2b(v1); o.z = f2b(v2); o.w = f2b(v3);
        *(ushort4*)&((u16*)Cout)[(size_t)row * N + col] = o;
      }
    }
  }
}

// ---------------------------------------------------------------------------
// reduce: out = P0 + P1 + bias[col] + res. N fixed 1024. float4 per thread.
// ---------------------------------------------------------------------------
__global__ __launch_bounds__(256) void reduce_add(
    const float* __restrict__ P0, const float* __restrict__ P1,
    const float* __restrict__ bias, const float* __restrict__ res,
    float* __restrict__ out) {
  const int idx = blockIdx.x * 256 + threadIdx.x;  // float4 index
  const float4 a = ((const float4*)P0)[idx];
  const float4 b = ((const float4*)P1)[idx];
  const float4 c = ((const float4*)res)[idx];
  const float4 g = ((const float4*)bias)[idx & 255];  // 1024/4 = 256
  float4 o;
  o.x = a.x + b.x + c.x + g.x;
  o.y = a.y + b.y + c.y + g.y;
  o.z = a.z + b.z + c.z + g.z;
  o.w = a.w + b.w + c.w + g.w;
  ((float4*)out)[idx] = o;
}

// ---------------------------------------------------------------------------
// Flash attention (causal), LDS-staged double-buffered K/V, triangle-paired.
// Transposed math: S^T = mfma(K,Q) -> per-lane scalar softmax state,
// O^T = mfma(V^T,P^T) -> in-lane rescale. Staging addresses hoisted,
// P packed with v_perm truncation.
// ---------------------------------------------------------------------------
__global__ __launch_bounds__(256) void attn_fwd(
    const u16* __restrict__ Q, const u16* __restrict__ Kb,
    const u16* __restrict__ Vt, u16* __restrict__ Y) {
  const int bh = blockIdx.y;
  const int pair = blockIdx.x;
  const int nqt = (int)(T_SEQ / 64);
  const int tid = threadIdx.x;
  const int wave = tid >> 6, lane = tid & 63;
  const int quad = lane >> 4, l16 = lane & 15;
  const int sw = l16 & 7;  // xor-swizzle key for frag reads
  const u16* Qp = Q + (size_t)bh * T_SEQ * HEAD_D;
  const u16* Kp = Kb + (size_t)bh * T_SEQ * HEAD_D;
  const u16* Vp = Vt + (size_t)bh * HEAD_D * T_SEQ;

  __shared__ u16 Ks[2][64 * 64];
  __shared__ u16 Vs[2][64 * 64];
  __shared__ u16 Pl[4][16 * 72];

  // loop-invariant staging geometry (chunk c -> row c>>3, col8 (c&7)^(row&7))
  const int c1 = tid, c2 = tid + 256;
  const int r1 = c1 >> 3, g1 = ((c1 & 7) ^ (r1 & 7)) * 8;
  const int r2 = c2 >> 3, g2 = ((c2 & 7) ^ (r2 & 7)) * 8;
  const size_t kO1 = (size_t)r1 * HEAD_D + g1, kO2 = (size_t)r2 * HEAD_D + g2;
  const size_t vO1 = (size_t)r1 * T_SEQ + g1, vO2 = (size_t)r2 * T_SEQ + g2;
  u16* const dK1[2] = {&Ks[0][c1 * 8], &Ks[1][c1 * 8]};
  u16* const dK2[2] = {&Ks[0][c2 * 8], &Ks[1][c2 * 8]};
  u16* const dV1[2] = {&Vs[0][c1 * 8], &Vs[1][c1 * 8]};
  u16* const dV2[2] = {&Vs[0][c2 * 8], &Vs[1][c2 * 8]};

  auto stageK = [&](int bb, int k0) {
    const u16* base = Kp + (size_t)k0 * HEAD_D;
    load_lds16(base + kO1, dK1[bb]);
    load_lds16(base + kO2, dK2[bb]);
  };
  auto stageV = [&](int bb, int k0) {
    const u16* base = Vp + k0;
    load_lds16(base + vO1, dV1[bb]);
    load_lds16(base + vO2, dV2[bb]);
  };

  const int b = bh >> 4, h = bh & 15;

#pragma unroll 1
  for (int phase = 0; phase < 2; ++phase) {
    const int qb = phase == 0 ? (nqt - 1 - pair) : pair;
    const int q0 = qb * 64;
    const int qglob = q0 + wave * 16 + l16;  // this lane's q row

    if (phase == 1) __syncthreads();  // protect Ks/Vs from prior readers

    bf16x8 qF[2];
    qF[0] = *(const bf16x8*)&Qp[(size_t)qglob * HEAD_D + quad * 8];
    qF[1] = *(const bf16x8*)&Qp[(size_t)qglob * HEAD_D + 32 + quad * 8];

    f32x4 o[4] = {};   // O^T: d = nt*16 + quad*4 + r, q = l16
    float mrun = -3e38f, lrun = 0.0f;

    stageK(0, 0);
    stageV(0, 0);

    int buf = 0;
    for (int kb = 0; kb <= qb; ++kb) {
      const int k0 = kb * 64;
      __syncthreads();  // drains DMA + all waves' prior-buffer reads
      if (kb < qb) {
        stageK(buf ^ 1, k0 + 64);
        stageV(buf ^ 1, k0 + 64);
      }
      // S^T: key = nt*16 + quad*4 + r (rows), q = l16 (cols)
      f32x4 st[4] = {};
#pragma unroll
      for (int ks = 0; ks < 2; ++ks) {
#pragma unroll
        for (int nt = 0; nt < 4; ++nt) {
          bf16x8 kF = *(const bf16x8*)
              &Ks[buf][(nt * 16 + l16) * 64 + (((ks * 4 + quad) ^ sw) * 8)];
          st[nt] = __builtin_amdgcn_mfma_f32_16x16x32_bf16(kF, qF[ks], st[nt],
                                                           0, 0, 0);
        }
      }
      if (kb == qb) {  // causal mask, diagonal tile only
#pragma unroll
        for (int nt = 0; nt < 4; ++nt) {
#pragma unroll
          for (int r = 0; r < 4; ++r) {
            const int key = k0 + nt * 16 + quad * 4 + r;
            if (key > qglob) st[nt][r] = -3e38f;
          }
        }
      }
      // online softmax over keys: register tree + cross-quad (lanes ^16,^32)
      float m = st[0][0];
#pragma unroll
      for (int nt = 0; nt < 4; ++nt)
#pragma unroll
        for (int r = 0; r < 4; ++r) m = fmaxf(m, st[nt][r]);
      m = fmaxf(m, __shfl_xor(m, 16, 64));
      m = fmaxf(m, __shfl_xor(m, 32, 64));
      const float nm = fmaxf(mrun, m);
      const float alpha = __builtin_amdgcn_exp2f(mrun - nm);
      mrun = nm;
      float sum = 0.0f;
#pragma unroll
      for (int nt = 0; nt < 4; ++nt)
#pragma unroll
        for (int r = 0; r < 4; ++r) {
          const float p = __builtin_amdgcn_exp2f(st[nt][r] - nm);
          st[nt][r] = p;
          sum += p;
        }
      sum += __shfl_xor(sum, 16, 64);
      sum += __shfl_xor(sum, 32, 64);
      lrun = lrun * alpha + sum;
#pragma unroll
      for (int nt = 0; nt < 4; ++nt)
#pragma unroll
        for (int r = 0; r < 4; ++r) o[nt][r] *= alpha;
      // P^T -> LDS: row = q (l16), col = key; v_perm truncating pack
#pragma unroll
      for (int nt = 0; nt < 4; ++nt) {
        uint2 pk;
        pk.x = pk2(st[nt][0], st[nt][1]);
        pk.y = pk2(st[nt][2], st[nt][3]);
        *(uint2*)&Pl[wave][l16 * 72 + nt * 16 + quad * 4] = pk;
      }
      // O^T += V^T P^T  (A = V^T from Vs, B = P^T from Pl)
#pragma unroll
      for (int ks = 0; ks < 2; ++ks) {
        bf16x8 aP = *(const bf16x8*)&Pl[wave][l16 * 72 + ks * 32 + quad * 8];
#pragma unroll
        for (int nt = 0; nt < 4; ++nt) {
          bf16x8 vF = *(const bf16x8*)
              &Vs[buf][(nt * 16 + l16) * 64 + (((ks * 4 + quad) ^ sw) * 8)];
          o[nt] =
              __builtin_amdgcn_mfma_f32_16x16x32_bf16(vF, aP, o[nt], 0, 0, 0);
        }
      }
      buf ^= 1;
    }

    // write O^T / l -> Y bf16 [B,T,C]: row = token (l16), cols = d
    const float rl = 1.0f / lrun;
    u16* yp = Y + ((size_t)(b * T_SEQ + qglob)) * C_EMBD + h * HEAD_D;
#pragma unroll
    for (int nt = 0; nt < 4; ++nt) {
      ushort4 ov;
      ov.x = f2b(o[nt][0] * rl); ov.y = f2b(o[nt][1] * rl);
      ov.z = f2b(o[nt][2] * rl); ov.w = f2b(o[nt][3] * rl);
      *(ushort4*)&yp[nt * 16 + quad * 4] = ov;
    }
  }
}

// ---------------------------------------------------------------------------
// Host side
// ---------------------------------------------------------------------------
extern "C" void kernel_launch(void* const* d_in, const int* in_sizes, int n_in,
                              void* d_out, int out_size, void* d_ws,
                              size_t ws_size, hipStream_t stream) {
  const float* x      = (const float*)d_in[0];
  const float* W_attn = (const float*)d_in[1];
  const float* b_attn = (const float*)d_in[2];
  const float* W_proj = (const float*)d_in[3];
  const float* b_proj = (const float*)d_in[4];
  const float* W_fc   = (const float*)d_in[5];
  const float* b_fc   = (const float*)d_in[6];
  const float* W_fc2  = (const float*)d_in[7];
  const float* b_fc2  = (const float*)d_in[8];
  const float* ln1_g  = (const float*)d_in[9];
  const float* ln1_b  = (const float*)d_in[10];
  const float* ln2_g  = (const float*)d_in[11];
  const float* ln2_b  = (const float*)d_in[12];

  u16* wqkvT = (u16*)d_ws;                            // [3072][1024] bf16
  u16* wprojT = wqkvT + (size_t)3072 * 1024;          // [1024][1024]
  u16* wfcT  = wprojT + (size_t)1024 * 1024;          // [4096][1024]
  u16* wfc2T = wfcT + (size_t)4096 * 1024;            // [1024][4096]
  u16* Abuf  = wfc2T + (size_t)1024 * 4096;           // [4096][1024] bf16
  float* x1  = (float*)(Abuf + (size_t)M_TOK * C_EMBD);  // [4096][1024] f32
  u16* hbuf  = (u16*)(x1 + (size_t)M_TOK * C_EMBD);   // [4096][4096] bf16, 32MB
  float* projP = (float*)hbuf;                        // proj partials 2x16MB (dead window)
  u16* Qb    = hbuf + (size_t)M_TOK * 4096;           // [32][2048][64]
  u16* Kbuf  = Qb + (size_t)32 * T_SEQ * HEAD_D;
  u16* Vtb   = Kbuf + (size_t)32 * T_SEQ * HEAD_D;
  float* fc2P1 = (float*)Qb;                          // fc2 partial z=1 (16MB, dead)

  const dim3 blk(256);

  transpose_cast<<<dim3(3072 / 32, 1024 / 32), blk, 0, stream>>>(W_attn, wqkvT, 1024, 3072);
  transpose_cast<<<dim3(1024 / 32, 1024 / 32), blk, 0, stream>>>(W_proj, wprojT, 1024, 1024);
  transpose_cast<<<dim3(4096 / 32, 1024 / 32), blk, 0, stream>>>(W_fc, wfcT, 1024, 4096);
  transpose_cast<<<dim3(1024 / 32, 4096 / 32), blk, 0, stream>>>(W_fc2, wfc2T, 4096, 1024);

  ln_cast<<<M_TOK, blk, 0, stream>>>(x, ln1_g, ln1_b, Abuf);

  // qkv GEMM with fused split/reorder/scale epilogue
  gemm_bt<EPI_QKV, 1><<<dim3(3072 / 128, M_TOK / 128), blk, 0, stream>>>(
      Abuf, wqkvT, b_attn, Qb, Kbuf, Vtb, M_TOK, 3072, 1024);

  attn_fwd<<<dim3(T_SEQ / 128, 32), blk, 0, stream>>>(Qb, Kbuf, Vtb, Abuf);

  // proj: split-K=2 partials into hbuf region, then reduce (+bias+x) -> x1
  gemm_bt<EPI_PART, 2><<<dim3(1024 / 128, M_TOK / 128, 2), blk, 0, stream>>>(
      Abuf, wprojT, nullptr, projP, projP + (size_t)M_TOK * C_EMBD, nullptr,
      M_TOK, 1024, 1024);
  reduce_add<<<M_TOK * C_EMBD / 1024, blk, 0, stream>>>(
      projP, projP + (size_t)M_TOK * C_EMBD, b_proj, x, x1);

  ln_cast<<<M_TOK, blk, 0, stream>>>(x1, ln2_g, ln2_b, Abuf);

  gemm_bt<EPI_GELU_BF16, 1><<<dim3(4096 / 128, M_TOK / 128), blk, 0, stream>>>(
      Abuf, wfcT, b_fc, hbuf, nullptr, nullptr, M_TOK, 4096, 1024);

  // fc2: split-K=2, partial z=0 -> d_out, z=1 -> dead Q/K region, reduce in place
  gemm_bt<EPI_PART, 2><<<dim3(1024 / 128, M_TOK / 128, 2), blk, 0, stream>>>(
      hbuf, wfc2T, nullptr, d_out, fc2P1, nullptr, M_TOK, 1024, 4096);
  reduce_add<<<M_TOK * C_EMBD / 1024, blk, 0, stream>>>(
      (const float*)d_out, fc2P1, b_fc2, x1, (float*)d_out);
}

// Round 7
// 353.779 us; speedup vs baseline: 1.7295x; 1.0237x over previous
//
#include <hip/hip_runtime.h>
#include <cstdint>
#include <cstddef>

// ---------------------------------------------------------------------------
// Transformer block on MI355X (gfx950), bf16 MFMA path.
// R7: (1) L2-locality grid swizzle in all GEMMs (G=8 M-tiles per group,
//     N fastest within group) to kill the 8x HBM over-fetch seen in R6;
//     (2) proj reduce fused into ln2 (ln_reduce_cast).
// ---------------------------------------------------------------------------

typedef unsigned short u16;
typedef short bf16x8 __attribute__((ext_vector_type(8)));
typedef float f32x4 __attribute__((ext_vector_type(4)));

#define C_EMBD 1024
#define T_SEQ  2048
#define N_BATCH 2
#define N_HEADS 16
#define HEAD_D 64
#define M_TOK  4096   // N_BATCH * T_SEQ
#define Q_SCALE 0.18033688011112042f  // 1/sqrt(64) * log2(e)

__device__ __forceinline__ u16 f2b(float f) {
  union { float f; unsigned u; } v; v.f = f;
  unsigned r = (v.u + 0x7fffu + ((v.u >> 16) & 1u)) >> 16;  // RNE
  return (u16)r;
}
__device__ __forceinline__ float b2f(u16 u) {
  union { unsigned u; float f; } v; v.u = ((unsigned)u) << 16;
  return v.f;
}
// pack 2 fp32 -> bf16x2 by truncation: lo16 = a.hi16, hi16 = b.hi16 (1 VALU op)
__device__ __forceinline__ unsigned pk2(float a, float b) {
  union { float f; unsigned u; } x, y; x.f = a; y.f = b;
  return __builtin_amdgcn_perm(y.u, x.u, 0x07060302u);
}
__device__ __forceinline__ void load_lds16(const void* g, void* l) {
  __builtin_amdgcn_global_load_lds(
      (const __attribute__((address_space(1))) void*)g,
      (__attribute__((address_space(3))) void*)l, 16, 0, 0);
}
// tanh-form GELU in exp2 domain: x * t/(t+1), t = exp2(2.3021859*(x+0.044715x^3))
__device__ __forceinline__ float gelu_fast(float x) {
  const float p = x * __builtin_fmaf(0.044715f * x, x, 1.0f);
  const float t = __builtin_amdgcn_exp2f(2.3021859215f * p);
  return x * t * __builtin_amdgcn_rcpf(t + 1.0f);
}

// ---------------------------------------------------------------------------
// Weight transpose + cast: W[K][N] fp32 -> Wt[N][K] bf16
// ---------------------------------------------------------------------------
__global__ __launch_bounds__(256) void transpose_cast(
    const float* __restrict__ W, u16* __restrict__ Wt, int K, int N) {
  __shared__ float tile[32][33];
  const int n0 = blockIdx.x * 32, k0 = blockIdx.y * 32;
  const int tx = threadIdx.x & 31, ty = threadIdx.x >> 5;  // ty in [0,8)
#pragma unroll
  for (int i = 0; i < 32; i += 8)
    tile[ty + i][tx] = W[(size_t)(k0 + ty + i) * N + n0 + tx];
  __syncthreads();
#pragma unroll
  for (int i = 0; i < 32; i += 8)
    Wt[(size_t)(n0 + ty + i) * K + k0 + tx] = f2b(tile[tx][ty + i]);
}

// ---------------------------------------------------------------------------
// LayerNorm over rows of 1024 fp32 -> bf16 out. One block (256 thr) per row.
// ---------------------------------------------------------------------------
__global__ __launch_bounds__(256) void ln_cast(
    const float* __restrict__ X, const float* __restrict__ g,
    const float* __restrict__ b, u16* __restrict__ Y) {
  const int row = blockIdx.x;
  const int tid = threadIdx.x;
  const float4 v = ((const float4*)(X + (size_t)row * C_EMBD))[tid];
  float s = v.x + v.y + v.z + v.w;
  float ss = v.x * v.x + v.y * v.y + v.z * v.z + v.w * v.w;
#pragma unroll
  for (int off = 32; off > 0; off >>= 1) {
    s += __shfl_down(s, off, 64);
    ss += __shfl_down(ss, off, 64);
  }
  __shared__ float red[8];
  __shared__ float stats[2];
  const int wave = tid >> 6, lane = tid & 63;
  if (lane == 0) { red[wave] = s; red[4 + wave] = ss; }
  __syncthreads();
  if (tid == 0) {
    float S = red[0] + red[1] + red[2] + red[3];
    float SS = red[4] + red[5] + red[6] + red[7];
    float mu = S * (1.0f / C_EMBD);
    float var = SS * (1.0f / C_EMBD) - mu * mu;
    stats[0] = mu;
    stats[1] = rsqrtf(var + 1e-5f);
  }
  __syncthreads();
  const float mu = stats[0], rs = stats[1];
  const float4 gv = ((const float4*)g)[tid];
  const float4 bv = ((const float4*)b)[tid];
  ushort4 o;
  o.x = f2b((v.x - mu) * rs * gv.x + bv.x);
  o.y = f2b((v.y - mu) * rs * gv.y + bv.y);
  o.z = f2b((v.z - mu) * rs * gv.z + bv.z);
  o.w = f2b((v.w - mu) * rs * gv.w + bv.w);
  ((ushort4*)(Y + (size_t)row * C_EMBD))[tid] = o;
}

// ---------------------------------------------------------------------------
// Fused: x1 = P0 + P1 + bias + res (proj split-K reduce + residual), then
// LayerNorm(x1) -> bf16 Y. Writes both x1 (fp32) and Y. One block per row.
// ---------------------------------------------------------------------------
__global__ __launch_bounds__(256) void ln_reduce_cast(
    const float* __restrict__ P0, const float* __restrict__ P1,
    const float* __restrict__ bias, const float* __restrict__ res,
    const float* __restrict__ g, const float* __restrict__ b,
    float* __restrict__ X1, u16* __restrict__ Y) {
  const int row = blockIdx.x;
  const int tid = threadIdx.x;
  const size_t base = (size_t)row * C_EMBD;
  const float4 p0 = ((const float4*)(P0 + base))[tid];
  const float4 p1 = ((const float4*)(P1 + base))[tid];
  const float4 rr = ((const float4*)(res + base))[tid];
  const float4 bb = ((const float4*)bias)[tid];
  float4 v;
  v.x = p0.x + p1.x + rr.x + bb.x;
  v.y = p0.y + p1.y + rr.y + bb.y;
  v.z = p0.z + p1.z + rr.z + bb.z;
  v.w = p0.w + p1.w + rr.w + bb.w;
  ((float4*)(X1 + base))[tid] = v;
  float s = v.x + v.y + v.z + v.w;
  float ss = v.x * v.x + v.y * v.y + v.z * v.z + v.w * v.w;
#pragma unroll
  for (int off = 32; off > 0; off >>= 1) {
    s += __shfl_down(s, off, 64);
    ss += __shfl_down(ss, off, 64);
  }
  __shared__ float red[8];
  __shared__ float stats[2];
  const int wave = tid >> 6, lane = tid & 63;
  if (lane == 0) { red[wave] = s; red[4 + wave] = ss; }
  __syncthreads();
  if (tid == 0) {
    float S = red[0] + red[1] + red[2] + red[3];
    float SS = red[4] + red[5] + red[6] + red[7];
    float mu = S * (1.0f / C_EMBD);
    float var = SS * (1.0f / C_EMBD) - mu * mu;
    stats[0] = mu;
    stats[1] = rsqrtf(var + 1e-5f);
  }
  __syncthreads();
  const float mu = stats[0], rs = stats[1];
  const float4 gv = ((const float4*)g)[tid];
  const float4 bv = ((const float4*)b)[tid];
  ushort4 o;
  o.x = f2b((v.x - mu) * rs * gv.x + bv.x);
  o.y = f2b((v.y - mu) * rs * gv.y + bv.y);
  o.z = f2b((v.z - mu) * rs * gv.z + bv.z);
  o.w = f2b((v.w - mu) * rs * gv.w + bv.w);
  ((ushort4*)(Y + base))[tid] = o;
}

// ---------------------------------------------------------------------------
// GEMM: C[M,N] = A[M,K](bf16) * Bt[N,K](bf16)^T (+epilogue). BK=64,
// xor-swizzled LDS, transposed acc (C^T). 128x128 tile, 4 waves (2x2).
// Grid swizzle: groups of G=8 M-tiles, N fastest within a group -> the
// co-resident working set (A slice + B slice) fits L2/L3, killing re-fetch.
// SPLIT=2: blockIdx.z selects K-half, raw f32 partials to Cout/Cout2.
// ---------------------------------------------------------------------------
enum { EPI_BF16 = 0, EPI_GELU_BF16 = 2, EPI_PART = 3, EPI_QKV = 4 };

template <int EPI, int SPLIT>
__global__ __launch_bounds__(256) void gemm_bt(
    const u16* __restrict__ A, const u16* __restrict__ Bt,
    const float* __restrict__ bias,
    void* __restrict__ Cout, void* __restrict__ Cout2, void* __restrict__ Cout3,
    int M, int N, int K) {
  __shared__ u16 As[128 * 64];
  __shared__ u16 Bs[128 * 64];
  const int tid = threadIdx.x;
  const int wave = tid >> 6, lane = tid & 63;
  const int quad = lane >> 4, l16 = lane & 15;
  const int sw = l16 & 7;

  // L2-locality swizzle (numM = gridDim.y must be divisible by G=8)
  const int nBx = (int)gridDim.x;
  const int id = (int)blockIdx.y * nBx + (int)blockIdx.x;
  const int span = 8 * nBx;
  const int gid = id / span, rem = id % span;
  const int mt = gid * 8 + (rem & 7), nt_ = rem >> 3;
  const int m0 = mt * 128, n0 = nt_ * 128;

  const int wm = (wave >> 1) * 64, wn = (wave & 1) * 64;

  f32x4 acc[4][4] = {};  // acc[tm][tn][r]: m = wm+tm*16+l16, n = wn+tn*16+quad*4+r

  const int kTiles = (K >> 6) / SPLIT;
  const int kt0 = (SPLIT == 2) ? (int)blockIdx.z * kTiles : 0;
  for (int kt = kt0; kt < kt0 + kTiles; ++kt) {
    const int k0 = kt << 6;
    // stage 128x64: 1024 chunks each, 4/thread; col8 xor-swizzled by row&7
#pragma unroll
    for (int i = 0; i < 4; ++i) {
      const int c = tid + i * 256;
      const int row = c >> 3, gc = ((c & 7) ^ (row & 7)) * 8;
      load_lds16(A + (size_t)(m0 + row) * K + k0 + gc, &As[c * 8]);
    }
#pragma unroll
    for (int i = 0; i < 4; ++i) {
      const int c = tid + i * 256;
      const int row = c >> 3, gc = ((c & 7) ^ (row & 7)) * 8;
      load_lds16(Bt + (size_t)(n0 + row) * K + k0 + gc, &Bs[c * 8]);
    }
    __syncthreads();
#pragma unroll
    for (int ks = 0; ks < 2; ++ks) {
      bf16x8 aF[4], bF[4];
#pragma unroll
      for (int t = 0; t < 4; ++t) {
        aF[t] = *(const bf16x8*)
            &As[(wm + t * 16 + l16) * 64 + (((ks * 4 + quad) ^ sw) * 8)];
        bF[t] = *(const bf16x8*)
            &Bs[(wn + t * 16 + l16) * 64 + (((ks * 4 + quad) ^ sw) * 8)];
      }
#pragma unroll
      for (int tm = 0; tm < 4; ++tm)
#pragma unroll
        for (int tn = 0; tn < 4; ++tn)
          acc[tm][tn] = __builtin_amdgcn_mfma_f32_16x16x32_bf16(
              bF[tn], aF[tm], acc[tm][tn], 0, 0, 0);  // transposed: C^T
    }
    __syncthreads();
  }

  float* Pz = (float*)((SPLIT == 2 && blockIdx.z == 1) ? Cout2 : Cout);
#pragma unroll
  for (int tm = 0; tm < 4; ++tm) {
    const int row = m0 + wm + tm * 16 + l16;
#pragma unroll
    for (int tn = 0; tn < 4; ++tn) {
      const int col = n0 + wn + tn * 16 + quad * 4;
      if constexpr (EPI == EPI_PART) {
        *(float4*)&Pz[(size_t)row * N + col] = *(float4*)&acc[tm][tn];
      } else if constexpr (EPI == EPI_QKV) {
        // row = token; col in [0,3072): [0,1024)=Q, [1024,2048)=K, rest=V
        const int bb = row >> 11, t = row & (T_SEQ - 1);
        const float4 bz = *(const float4*)&bias[col];
        float v0 = acc[tm][tn][0] + bz.x, v1 = acc[tm][tn][1] + bz.y;
        float v2 = acc[tm][tn][2] + bz.z, v3 = acc[tm][tn][3] + bz.w;
        const int sec = col >> 10;           // wave-uniform (16-col group)
        const int h = (col & 1023) >> 6, d4 = col & 63;
        const int bh = bb * N_HEADS + h;
        if (sec == 0) {                      // Q, pre-scaled
          ushort4 o;
          o.x = f2b(v0 * Q_SCALE); o.y = f2b(v1 * Q_SCALE);
          o.z = f2b(v2 * Q_SCALE); o.w = f2b(v3 * Q_SCALE);
          *(ushort4*)&((u16*)Cout)[((size_t)bh * T_SEQ + t) * HEAD_D + d4] = o;
        } else if (sec == 1) {               // K
          ushort4 o;
          o.x = f2b(v0); o.y = f2b(v1); o.z = f2b(v2); o.w = f2b(v3);
          *(ushort4*)&((u16*)Cout2)[((size_t)bh * T_SEQ + t) * HEAD_D + d4] = o;
        } else {                             // V^T: [bh][d][t]
          u16* vp = (u16*)Cout3 + ((size_t)bh * HEAD_D + d4) * T_SEQ + t;
          vp[0] = f2b(v0); vp[T_SEQ] = f2b(v1);
          vp[2 * T_SEQ] = f2b(v2); vp[3 * T_SEQ] = f2b(v3);
        }
      } else {
        const float4 bz = *(const float4*)&bias[col];
        float v0 = acc[tm][tn][0] + bz.x, v1 = acc[tm][tn][1] + bz.y;
        float v2 = acc[tm][tn][2] + bz.z, v3 = acc[tm][tn][3] + bz.w;
        if constexpr (EPI == EPI_GELU_BF16) {
          v0 = gelu_fast(v0); v1 = gelu_fast(v1);
          v2 = gelu_fast(v2); v3 = gelu_fast(v3);
        }
        ushort4 o;
        o.x = f2b(v0); o.y = f2b(v1); o.z = f2b(v2); o.w = f2b(v3);
        *(ushort4*)&((u16*)Cout)[(size_t)row * N + col] = o;
      }
    }
  }
}

// ---------------------------------------------------------------------------
// reduce: out = P0 + P1 + bias[col] + res. N fixed 1024. float4 per thread.
// ---------------------------------------------------------------------------
__global__ __launch_bounds__(256) void reduce_add(
    const float* __restrict__ P0, const float* __restrict__ P1,
    const float* __restrict__ bias, const float* __restrict__ res,
    float* __restrict__ out) {
  const int idx = blockIdx.x * 256 + threadIdx.x;  // float4 index
  const float4 a = ((const float4*)P0)[idx];
  const float4 b = ((const float4*)P1)[idx];
  const float4 c = ((const float4*)res)[idx];
  const float4 g = ((const float4*)bias)[idx & 255];  // 1024/4 = 256
  float4 o;
  o.x = a.x + b.x + c.x + g.x;
  o.y = a.y + b.y + c.y + g.y;
  o.z = a.z + b.z + c.z + g.z;
  o.w = a.w + b.w + c.w + g.w;
  ((float4*)out)[idx] = o;
}

// ---------------------------------------------------------------------------
// Flash attention (causal), LDS-staged double-buffered K/V, triangle-paired.
// Transposed math: S^T = mfma(K,Q) -> per-lane scalar softmax state,
// O^T = mfma(V^T,P^T) -> in-lane rescale. Staging addresses hoisted,
// P packed with v_perm truncation.
// ---------------------------------------------------------------------------
__global__ __launch_bounds__(256) void attn_fwd(
    const u16* __restrict__ Q, const u16* __restrict__ Kb,
    const u16* __restrict__ Vt, u16* __restrict__ Y) {
  const int bh = blockIdx.y;
  const int pair = blockIdx.x;
  const int nqt = (int)(T_SEQ / 64);
  const int tid = threadIdx.x;
  const int wave = tid >> 6, lane = tid & 63;
  const int quad = lane >> 4, l16 = lane & 15;
  const int sw = l16 & 7;  // xor-swizzle key for frag reads
  const u16* Qp = Q + (size_t)bh * T_SEQ * HEAD_D;
  const u16* Kp = Kb + (size_t)bh * T_SEQ * HEAD_D;
  const u16* Vp = Vt + (size_t)bh * HEAD_D * T_SEQ;

  __shared__ u16 Ks[2][64 * 64];
  __shared__ u16 Vs[2][64 * 64];
  __shared__ u16 Pl[4][16 * 72];

  // loop-invariant staging geometry (chunk c -> row c>>3, col8 (c&7)^(row&7))
  const int c1 = tid, c2 = tid + 256;
  const int r1 = c1 >> 3, g1 = ((c1 & 7) ^ (r1 & 7)) * 8;
  const int r2 = c2 >> 3, g2 = ((c2 & 7) ^ (r2 & 7)) * 8;
  const size_t kO1 = (size_t)r1 * HEAD_D + g1, kO2 = (size_t)r2 * HEAD_D + g2;
  const size_t vO1 = (size_t)r1 * T_SEQ + g1, vO2 = (size_t)r2 * T_SEQ + g2;
  u16* const dK1[2] = {&Ks[0][c1 * 8], &Ks[1][c1 * 8]};
  u16* const dK2[2] = {&Ks[0][c2 * 8], &Ks[1][c2 * 8]};
  u16* const dV1[2] = {&Vs[0][c1 * 8], &Vs[1][c1 * 8]};
  u16* const dV2[2] = {&Vs[0][c2 * 8], &Vs[1][c2 * 8]};

  auto stageK = [&](int bb, int k0) {
    const u16* base = Kp + (size_t)k0 * HEAD_D;
    load_lds16(base + kO1, dK1[bb]);
    load_lds16(base + kO2, dK2[bb]);
  };
  auto stageV = [&](int bb, int k0) {
    const u16* base = Vp + k0;
    load_lds16(base + vO1, dV1[bb]);
    load_lds16(base + vO2, dV2[bb]);
  };

  const int b = bh >> 4, h = bh & 15;

#pragma unroll 1
  for (int phase = 0; phase < 2; ++phase) {
    const int qb = phase == 0 ? (nqt - 1 - pair) : pair;
    const int q0 = qb * 64;
    const int qglob = q0 + wave * 16 + l16;  // this lane's q row

    if (phase == 1) __syncthreads();  // protect Ks/Vs from prior readers

    bf16x8 qF[2];
    qF[0] = *(const bf16x8*)&Qp[(size_t)qglob * HEAD_D + quad * 8];
    qF[1] = *(const bf16x8*)&Qp[(size_t)qglob * HEAD_D + 32 + quad * 8];

    f32x4 o[4] = {};   // O^T: d = nt*16 + quad*4 + r, q = l16
    float mrun = -3e38f, lrun = 0.0f;

    stageK(0, 0);
    stageV(0, 0);

    int buf = 0;
    for (int kb = 0; kb <= qb; ++kb) {
      const int k0 = kb * 64;
      __syncthreads();  // drains DMA + all waves' prior-buffer reads
      if (kb < qb) {
        stageK(buf ^ 1, k0 + 64);
        stageV(buf ^ 1, k0 + 64);
      }
      // S^T: key = nt*16 + quad*4 + r (rows), q = l16 (cols)
      f32x4 st[4] = {};
#pragma unroll
      for (int ks = 0; ks < 2; ++ks) {
#pragma unroll
        for (int nt = 0; nt < 4; ++nt) {
          bf16x8 kF = *(const bf16x8*)
              &Ks[buf][(nt * 16 + l16) * 64 + (((ks * 4 + quad) ^ sw) * 8)];
          st[nt] = __builtin_amdgcn_mfma_f32_16x16x32_bf16(kF, qF[ks], st[nt],
                                                           0, 0, 0);
        }
      }
      if (kb == qb) {  // causal mask, diagonal tile only
#pragma unroll
        for (int nt = 0; nt < 4; ++nt) {
#pragma unroll
          for (int r = 0; r < 4; ++r) {
            const int key = k0 + nt * 16 + quad * 4 + r;
            if (key > qglob) st[nt][r] = -3e38f;
          }
        }
      }
      // online softmax over keys: register tree + cross-quad (lanes ^16,^32)
      float m = st[0][0];
#pragma unroll
      for (int nt = 0; nt < 4; ++nt)
#pragma unroll
        for (int r = 0; r < 4; ++r) m = fmaxf(m, st[nt][r]);
      m = fmaxf(m, __shfl_xor(m, 16, 64));
      m = fmaxf(m, __shfl_xor(m, 32, 64));
      const float nm = fmaxf(mrun, m);
      const float alpha = __builtin_amdgcn_exp2f(mrun - nm);
      mrun = nm;
      float sum = 0.0f;
#pragma unroll
      for (int nt = 0; nt < 4; ++nt)
#pragma unroll
        for (int r = 0; r < 4; ++r) {
          const float p = __builtin_amdgcn_exp2f(st[nt][r] - nm);
          st[nt][r] = p;
          sum += p;
        }
      sum += __shfl_xor(sum, 16, 64);
      sum += __shfl_xor(sum, 32, 64);
      lrun = lrun * alpha + sum;
#pragma unroll
      for (int nt = 0; nt < 4; ++nt)
#pragma unroll
        for (int r = 0; r < 4; ++r) o[nt][r] *= alpha;
      // P^T -> LDS: row = q (l16), col = key; v_perm truncating pack
#pragma unroll
      for (int nt = 0; nt < 4; ++nt) {
        uint2 pk;
        pk.x = pk2(st[nt][0], st[nt][1]);
        pk.y = pk2(st[nt][2], st[nt][3]);
        *(uint2*)&Pl[wave][l16 * 72 + nt * 16 + quad * 4] = pk;
      }
      // O^T += V^T P^T  (A = V^T from Vs, B = P^T from Pl)
#pragma unroll
      for (int ks = 0; ks < 2; ++ks) {
        bf16x8 aP = *(const bf16x8*)&Pl[wave][l16 * 72 + ks * 32 + quad * 8];
#pragma unroll
        for (int nt = 0; nt < 4; ++nt) {
          bf16x8 vF = *(const bf16x8*)
              &Vs[buf][(nt * 16 + l16) * 64 + (((ks * 4 + quad) ^ sw) * 8)];
          o[nt] =
              __builtin_amdgcn_mfma_f32_16x16x32_bf16(vF, aP, o[nt], 0, 0, 0);
        }
      }
      buf ^= 1;
    }

    // write O^T / l -> Y bf16 [B,T,C]: row = token (l16), cols = d
    const float rl = 1.0f / lrun;
    u16* yp = Y + ((size_t)(b * T_SEQ + qglob)) * C_EMBD + h * HEAD_D;
#pragma unroll
    for (int nt = 0; nt < 4; ++nt) {
      ushort4 ov;
      ov.x = f2b(o[nt][0] * rl); ov.y = f2b(o[nt][1] * rl);
      ov.z = f2b(o[nt][2] * rl); ov.w = f2b(o[nt][3] * rl);
      *(ushort4*)&yp[nt * 16 + quad * 4] = ov;
    }
  }
}

// ---------------------------------------------------------------------------
// Host side
// ---------------------------------------------------------------------------
extern "C" void kernel_launch(void* const* d_in, const int* in_sizes, int n_in,
                              void* d_out, int out_size, void* d_ws,
                              size_t ws_size, hipStream_t stream) {
  const float* x      = (const float*)d_in[0];
  const float* W_attn = (const float*)d_in[1];
  const float* b_attn = (const float*)d_in[2];
  const float* W_proj = (const float*)d_in[3];
  const float* b_proj = (const float*)d_in[4];
  const float* W_fc   = (const float*)d_in[5];
  const float* b_fc   = (const float*)d_in[6];
  const float* W_fc2  = (const float*)d_in[7];
  const float* b_fc2  = (const float*)d_in[8];
  const float* ln1_g  = (const float*)d_in[9];
  const float* ln1_b  = (const float*)d_in[10];
  const float* ln2_g  = (const float*)d_in[11];
  const float* ln2_b  = (const float*)d_in[12];

  u16* wqkvT = (u16*)d_ws;                            // [3072][1024] bf16
  u16* wprojT = wqkvT + (size_t)3072 * 1024;          // [1024][1024]
  u16* wfcT  = wprojT + (size_t)1024 * 1024;          // [4096][1024]
  u16* wfc2T = wfcT + (size_t)4096 * 1024;            // [1024][4096]
  u16* Abuf  = wfc2T + (size_t)1024 * 4096;           // [4096][1024] bf16
  float* x1  = (float*)(Abuf + (size_t)M_TOK * C_EMBD);  // [4096][1024] f32
  u16* hbuf  = (u16*)(x1 + (size_t)M_TOK * C_EMBD);   // [4096][4096] bf16, 32MB
  float* projP = (float*)hbuf;                        // proj partials 2x16MB (dead window)
  u16* Qb    = hbuf + (size_t)M_TOK * 4096;           // [32][2048][64]
  u16* Kbuf  = Qb + (size_t)32 * T_SEQ * HEAD_D;
  u16* Vtb   = Kbuf + (size_t)32 * T_SEQ * HEAD_D;
  float* fc2P1 = (float*)Qb;                          // fc2 partial z=1 (16MB, dead)

  const dim3 blk(256);

  transpose_cast<<<dim3(3072 / 32, 1024 / 32), blk, 0, stream>>>(W_attn, wqkvT, 1024, 3072);
  transpose_cast<<<dim3(1024 / 32, 1024 / 32), blk, 0, stream>>>(W_proj, wprojT, 1024, 1024);
  transpose_cast<<<dim3(4096 / 32, 1024 / 32), blk, 0, stream>>>(W_fc, wfcT, 1024, 4096);
  transpose_cast<<<dim3(1024 / 32, 4096 / 32), blk, 0, stream>>>(W_fc2, wfc2T, 4096, 1024);

  ln_cast<<<M_TOK, blk, 0, stream>>>(x, ln1_g, ln1_b, Abuf);

  // qkv GEMM with fused split/reorder/scale epilogue
  gemm_bt<EPI_QKV, 1><<<dim3(3072 / 128, M_TOK / 128), blk, 0, stream>>>(
      Abuf, wqkvT, b_attn, Qb, Kbuf, Vtb, M_TOK, 3072, 1024);

  attn_fwd<<<dim3(T_SEQ / 128, 32), blk, 0, stream>>>(Qb, Kbuf, Vtb, Abuf);

  // proj: split-K=2 partials into hbuf region; reduce fused into ln2
  gemm_bt<EPI_PART, 2><<<dim3(1024 / 128, M_TOK / 128, 2), blk, 0, stream>>>(
      Abuf, wprojT, nullptr, projP, projP + (size_t)M_TOK * C_EMBD, nullptr,
      M_TOK, 1024, 1024);
  ln_reduce_cast<<<M_TOK, blk, 0, stream>>>(
      projP, projP + (size_t)M_TOK * C_EMBD, b_proj, x, ln2_g, ln2_b,
      x1, Abuf);

  gemm_bt<EPI_GELU_BF16, 1><<<dim3(4096 / 128, M_TOK / 128), blk, 0, stream>>>(
      Abuf, wfcT, b_fc, hbuf, nullptr, nullptr, M_TOK, 4096, 1024);

  // fc2: split-K=2, partial z=0 -> d_out, z=1 -> dead Q/K region, reduce in place
  gemm_bt<EPI_PART, 2><<<dim3(1024 / 128, M_TOK / 128, 2), blk, 0, stream>>>(
      hbuf, wfc2T, nullptr, d_out, fc2P1, nullptr, M_TOK, 1024, 4096);
  reduce_add<<<M_TOK * C_EMBD / 1024, blk, 0, stream>>>(
      (const float*)d_out, fc2P1, b_fc2, x1, (float*)d_out);
}

// Round 8
// 330.746 us; speedup vs baseline: 1.8499x; 1.0696x over previous
//
#include <hip/hip_runtime.h>
#include <cstdint>
#include <cstddef>

// ---------------------------------------------------------------------------
// Transformer block on MI355X (gfx950), bf16 MFMA path.
// R8: XCD-aware tile mapping (dispatcher round-robins block id % 8 across
//     XCDs; per-XCD 4 MB L2 is NOT shared) — GEMM: each XCD owns a 4-M-tile
//     slab (A resident, 1 MB) and walks N; attn: each XCD owns 4 heads
//     (K/V resident, 2 MB). Plus: 4 weight transposes fused into 1 kernel.
// ---------------------------------------------------------------------------

typedef unsigned short u16;
typedef short bf16x8 __attribute__((ext_vector_type(8)));
typedef float f32x4 __attribute__((ext_vector_type(4)));

#define C_EMBD 1024
#define T_SEQ  2048
#define N_BATCH 2
#define N_HEADS 16
#define HEAD_D 64
#define M_TOK  4096   // N_BATCH * T_SEQ
#define Q_SCALE 0.18033688011112042f  // 1/sqrt(64) * log2(e)

__device__ __forceinline__ u16 f2b(float f) {
  union { float f; unsigned u; } v; v.f = f;
  unsigned r = (v.u + 0x7fffu + ((v.u >> 16) & 1u)) >> 16;  // RNE
  return (u16)r;
}
__device__ __forceinline__ float b2f(u16 u) {
  union { unsigned u; float f; } v; v.u = ((unsigned)u) << 16;
  return v.f;
}
// pack 2 fp32 -> bf16x2 by truncation: lo16 = a.hi16, hi16 = b.hi16 (1 VALU op)
__device__ __forceinline__ unsigned pk2(float a, float b) {
  union { float f; unsigned u; } x, y; x.f = a; y.f = b;
  return __builtin_amdgcn_perm(y.u, x.u, 0x07060302u);
}
__device__ __forceinline__ void load_lds16(const void* g, void* l) {
  __builtin_amdgcn_global_load_lds(
      (const __attribute__((address_space(1))) void*)g,
      (__attribute__((address_space(3))) void*)l, 16, 0, 0);
}
// tanh-form GELU in exp2 domain: x * t/(t+1), t = exp2(2.3021859*(x+0.044715x^3))
__device__ __forceinline__ float gelu_fast(float x) {
  const float p = x * __builtin_fmaf(0.044715f * x, x, 1.0f);
  const float t = __builtin_amdgcn_exp2f(2.3021859215f * p);
  return x * t * __builtin_amdgcn_rcpf(t + 1.0f);
}

// ---------------------------------------------------------------------------
// Fused weight transpose + cast for all 4 weights: W[K][N] fp32 -> Wt[N][K] bf16
// Block-range decode; each block does one 32x32 tile. 256 threads.
// ---------------------------------------------------------------------------
__global__ __launch_bounds__(256) void transpose_cast_all(
    const float* __restrict__ W0, u16* __restrict__ D0,   // attn 1024x3072
    const float* __restrict__ W1, u16* __restrict__ D1,   // proj 1024x1024
    const float* __restrict__ W2, u16* __restrict__ D2,   // fc   1024x4096
    const float* __restrict__ W3, u16* __restrict__ D3) { // fc2  4096x1024
  int id = blockIdx.x;
  const float* W; u16* D; int K, N, t;
  if (id < 3072)      { W = W0; D = D0; K = 1024; N = 3072; t = id; }
  else if (id < 4096) { W = W1; D = D1; K = 1024; N = 1024; t = id - 3072; }
  else if (id < 8192) { W = W2; D = D2; K = 1024; N = 4096; t = id - 4096; }
  else                { W = W3; D = D3; K = 4096; N = 1024; t = id - 8192; }
  const int nTN = N >> 5;
  const int n0 = (t % nTN) * 32, k0 = (t / nTN) * 32;
  __shared__ float tile[32][33];
  const int tx = threadIdx.x & 31, ty = threadIdx.x >> 5;  // ty in [0,8)
#pragma unroll
  for (int i = 0; i < 32; i += 8)
    tile[ty + i][tx] = W[(size_t)(k0 + ty + i) * N + n0 + tx];
  __syncthreads();
#pragma unroll
  for (int i = 0; i < 32; i += 8)
    D[(size_t)(n0 + ty + i) * K + k0 + tx] = f2b(tile[tx][ty + i]);
}

// ---------------------------------------------------------------------------
// LayerNorm over rows of 1024 fp32 -> bf16 out. One block (256 thr) per row.
// ---------------------------------------------------------------------------
__global__ __launch_bounds__(256) void ln_cast(
    const float* __restrict__ X, const float* __restrict__ g,
    const float* __restrict__ b, u16* __restrict__ Y) {
  const int row = blockIdx.x;
  const int tid = threadIdx.x;
  const float4 v = ((const float4*)(X + (size_t)row * C_EMBD))[tid];
  float s = v.x + v.y + v.z + v.w;
  float ss = v.x * v.x + v.y * v.y + v.z * v.z + v.w * v.w;
#pragma unroll
  for (int off = 32; off > 0; off >>= 1) {
    s += __shfl_down(s, off, 64);
    ss += __shfl_down(ss, off, 64);
  }
  __shared__ float red[8];
  __shared__ float stats[2];
  const int wave = tid >> 6, lane = tid & 63;
  if (lane == 0) { red[wave] = s; red[4 + wave] = ss; }
  __syncthreads();
  if (tid == 0) {
    float S = red[0] + red[1] + red[2] + red[3];
    float SS = red[4] + red[5] + red[6] + red[7];
    float mu = S * (1.0f / C_EMBD);
    float var = SS * (1.0f / C_EMBD) - mu * mu;
    stats[0] = mu;
    stats[1] = rsqrtf(var + 1e-5f);
  }
  __syncthreads();
  const float mu = stats[0], rs = stats[1];
  const float4 gv = ((const float4*)g)[tid];
  const float4 bv = ((const float4*)b)[tid];
  ushort4 o;
  o.x = f2b((v.x - mu) * rs * gv.x + bv.x);
  o.y = f2b((v.y - mu) * rs * gv.y + bv.y);
  o.z = f2b((v.z - mu) * rs * gv.z + bv.z);
  o.w = f2b((v.w - mu) * rs * gv.w + bv.w);
  ((ushort4*)(Y + (size_t)row * C_EMBD))[tid] = o;
}

// ---------------------------------------------------------------------------
// Fused: x1 = P0 + P1 + bias + res (proj split-K reduce + residual), then
// LayerNorm(x1) -> bf16 Y. Writes both x1 (fp32) and Y. One block per row.
// ---------------------------------------------------------------------------
__global__ __launch_bounds__(256) void ln_reduce_cast(
    const float* __restrict__ P0, const float* __restrict__ P1,
    const float* __restrict__ bias, const float* __restrict__ res,
    const float* __restrict__ g, const float* __restrict__ b,
    float* __restrict__ X1, u16* __restrict__ Y) {
  const int row = blockIdx.x;
  const int tid = threadIdx.x;
  const size_t base = (size_t)row * C_EMBD;
  const float4 p0 = ((const float4*)(P0 + base))[tid];
  const float4 p1 = ((const float4*)(P1 + base))[tid];
  const float4 rr = ((const float4*)(res + base))[tid];
  const float4 bb = ((const float4*)bias)[tid];
  float4 v;
  v.x = p0.x + p1.x + rr.x + bb.x;
  v.y = p0.y + p1.y + rr.y + bb.y;
  v.z = p0.z + p1.z + rr.z + bb.z;
  v.w = p0.w + p1.w + rr.w + bb.w;
  ((float4*)(X1 + base))[tid] = v;
  float s = v.x + v.y + v.z + v.w;
  float ss = v.x * v.x + v.y * v.y + v.z * v.z + v.w * v.w;
#pragma unroll
  for (int off = 32; off > 0; off >>= 1) {
    s += __shfl_down(s, off, 64);
    ss += __shfl_down(ss, off, 64);
  }
  __shared__ float red[8];
  __shared__ float stats[2];
  const int wave = tid >> 6, lane = tid & 63;
  if (lane == 0) { red[wave] = s; red[4 + wave] = ss; }
  __syncthreads();
  if (tid == 0) {
    float S = red[0] + red[1] + red[2] + red[3];
    float SS = red[4] + red[5] + red[6] + red[7];
    float mu = S * (1.0f / C_EMBD);
    float var = SS * (1.0f / C_EMBD) - mu * mu;
    stats[0] = mu;
    stats[1] = rsqrtf(var + 1e-5f);
  }
  __syncthreads();
  const float mu = stats[0], rs = stats[1];
  const float4 gv = ((const float4*)g)[tid];
  const float4 bv = ((const float4*)b)[tid];
  ushort4 o;
  o.x = f2b((v.x - mu) * rs * gv.x + bv.x);
  o.y = f2b((v.y - mu) * rs * gv.y + bv.y);
  o.z = f2b((v.z - mu) * rs * gv.z + bv.z);
  o.w = f2b((v.w - mu) * rs * gv.w + bv.w);
  ((ushort4*)(Y + base))[tid] = o;
}

// ---------------------------------------------------------------------------
// GEMM: C[M,N] = A[M,K](bf16) * Bt[N,K](bf16)^T (+epilogue). BK=64,
// xor-swizzled LDS, transposed acc (C^T). 128x128 tile, 4 waves (2x2).
// XCD-aware map (requires gridDim.y == 32): XCD j = id%8 owns M-slab
// [4j,4j+4) — its A slice (1 MB) stays resident in its private L2; N walked
// with 4x consecutive B-tile reuse; B shared across XCDs via L3.
// SPLIT=2: blockIdx.z selects K-half, raw f32 partials to Cout/Cout2.
// ---------------------------------------------------------------------------
enum { EPI_BF16 = 0, EPI_GELU_BF16 = 2, EPI_PART = 3, EPI_QKV = 4 };

template <int EPI, int SPLIT>
__global__ __launch_bounds__(256) void gemm_bt(
    const u16* __restrict__ A, const u16* __restrict__ Bt,
    const float* __restrict__ bias,
    void* __restrict__ Cout, void* __restrict__ Cout2, void* __restrict__ Cout3,
    int M, int N, int K) {
  __shared__ u16 As[128 * 64];
  __shared__ u16 Bs[128 * 64];
  const int tid = threadIdx.x;
  const int wave = tid >> 6, lane = tid & 63;
  const int quad = lane >> 4, l16 = lane & 15;
  const int sw = l16 & 7;

  // XCD-aware swizzle (id%8 -> XCD round-robin heuristic; bijective, so
  // correctness is unaffected if the mapping assumption is wrong)
  const int id = (int)blockIdx.y * (int)gridDim.x + (int)blockIdx.x;
  const int mt = ((id & 7) << 2) + ((id >> 3) & 3);
  const int nt_ = id >> 5;
  const int m0 = mt * 128, n0 = nt_ * 128;

  const int wm = (wave >> 1) * 64, wn = (wave & 1) * 64;

  f32x4 acc[4][4] = {};  // acc[tm][tn][r]: m = wm+tm*16+l16, n = wn+tn*16+quad*4+r

  // loop-invariant staging geometry
  size_t aOff[4], bOff[4];
  int ldsOff[4];
#pragma unroll
  for (int i = 0; i < 4; ++i) {
    const int c = tid + i * 256;
    const int row = c >> 3, gc = ((c & 7) ^ (row & 7)) * 8;
    aOff[i] = (size_t)(m0 + row) * K + gc;
    bOff[i] = (size_t)(n0 + row) * K + gc;
    ldsOff[i] = c * 8;
  }

  const int kTiles = (K >> 6) / SPLIT;
  const int kt0 = (SPLIT == 2) ? (int)blockIdx.z * kTiles : 0;
  for (int kt = kt0; kt < kt0 + kTiles; ++kt) {
    const int k0 = kt << 6;
#pragma unroll
    for (int i = 0; i < 4; ++i)
      load_lds16(A + aOff[i] + k0, &As[ldsOff[i]]);
#pragma unroll
    for (int i = 0; i < 4; ++i)
      load_lds16(Bt + bOff[i] + k0, &Bs[ldsOff[i]]);
    __syncthreads();
#pragma unroll
    for (int ks = 0; ks < 2; ++ks) {
      bf16x8 aF[4], bF[4];
#pragma unroll
      for (int t = 0; t < 4; ++t) {
        aF[t] = *(const bf16x8*)
            &As[(wm + t * 16 + l16) * 64 + (((ks * 4 + quad) ^ sw) * 8)];
        bF[t] = *(const bf16x8*)
            &Bs[(wn + t * 16 + l16) * 64 + (((ks * 4 + quad) ^ sw) * 8)];
      }
#pragma unroll
      for (int tm = 0; tm < 4; ++tm)
#pragma unroll
        for (int tn = 0; tn < 4; ++tn)
          acc[tm][tn] = __builtin_amdgcn_mfma_f32_16x16x32_bf16(
              bF[tn], aF[tm], acc[tm][tn], 0, 0, 0);  // transposed: C^T
    }
    __syncthreads();
  }

  float* Pz = (float*)((SPLIT == 2 && blockIdx.z == 1) ? Cout2 : Cout);
#pragma unroll
  for (int tm = 0; tm < 4; ++tm) {
    const int row = m0 + wm + tm * 16 + l16;
#pragma unroll
    for (int tn = 0; tn < 4; ++tn) {
      const int col = n0 + wn + tn * 16 + quad * 4;
      if constexpr (EPI == EPI_PART) {
        *(float4*)&Pz[(size_t)row * N + col] = *(float4*)&acc[tm][tn];
      } else if constexpr (EPI == EPI_QKV) {
        // row = token; col in [0,3072): [0,1024)=Q, [1024,2048)=K, rest=V
        const int bb = row >> 11, t = row & (T_SEQ - 1);
        const float4 bz = *(const float4*)&bias[col];
        float v0 = acc[tm][tn][0] + bz.x, v1 = acc[tm][tn][1] + bz.y;
        float v2 = acc[tm][tn][2] + bz.z, v3 = acc[tm][tn][3] + bz.w;
        const int sec = col >> 10;           // wave-uniform (16-col group)
        const int h = (col & 1023) >> 6, d4 = col & 63;
        const int bh = bb * N_HEADS + h;
        if (sec == 0) {                      // Q, pre-scaled
          ushort4 o;
          o.x = f2b(v0 * Q_SCALE); o.y = f2b(v1 * Q_SCALE);
          o.z = f2b(v2 * Q_SCALE); o.w = f2b(v3 * Q_SCALE);
          *(ushort4*)&((u16*)Cout)[((size_t)bh * T_SEQ + t) * HEAD_D + d4] = o;
        } else if (sec == 1) {               // K
          ushort4 o;
          o.x = f2b(v0); o.y = f2b(v1); o.z = f2b(v2); o.w = f2b(v3);
          *(ushort4*)&((u16*)Cout2)[((size_t)bh * T_SEQ + t) * HEAD_D + d4] = o;
        } else {                             // V^T: [bh][d][t]
          u16* vp = (u16*)Cout3 + ((size_t)bh * HEAD_D + d4) * T_SEQ + t;
          vp[0] = f2b(v0); vp[T_SEQ] = f2b(v1);
          vp[2 * T_SEQ] = f2b(v2); vp[3 * T_SEQ] = f2b(v3);
        }
      } else {
        const float4 bz = *(const float4*)&bias[col];
        float v0 = acc[tm][tn][0] + bz.x, v1 = acc[tm][tn][1] + bz.y;
        float v2 = acc[tm][tn][2] + bz.z, v3 = acc[tm][tn][3] + bz.w;
        if constexpr (EPI == EPI_GELU_BF16) {
          v0 = gelu_fast(v0); v1 = gelu_fast(v1);
          v2 = gelu_fast(v2); v3 = gelu_fast(v3);
        }
        ushort4 o;
        o.x = f2b(v0); o.y = f2b(v1); o.z = f2b(v2); o.w = f2b(v3);
        *(ushort4*)&((u16*)Cout)[(size_t)row * N + col] = o;
      }
    }
  }
}

// ---------------------------------------------------------------------------
// reduce: out = P0 + P1 + bias[col] + res. N fixed 1024. float4 per thread.
// ---------------------------------------------------------------------------
__global__ __launch_bounds__(256) void reduce_add(
    const float* __restrict__ P0, const float* __restrict__ P1,
    const float* __restrict__ bias, const float* __restrict__ res,
    float* __restrict__ out) {
  const int idx = blockIdx.x * 256 + threadIdx.x;  // float4 index
  const float4 a = ((const float4*)P0)[idx];
  const float4 b = ((const float4*)P1)[idx];
  const float4 c = ((const float4*)res)[idx];
  const float4 g = ((const float4*)bias)[idx & 255];  // 1024/4 = 256
  float4 o;
  o.x = a.x + b.x + c.x + g.x;
  o.y = a.y + b.y + c.y + g.y;
  o.z = a.z + b.z + c.z + g.z;
  o.w = a.w + b.w + c.w + g.w;
  ((float4*)out)[idx] = o;
}

// ---------------------------------------------------------------------------
// Flash attention (causal), LDS-staged double-buffered K/V, triangle-paired.
// XCD-aware map: XCD j = id%8 serves heads {j, j+8, j+16, j+24} — K/V
// footprint 4 x 512 KB = 2 MB resident in its private L2.
// Transposed math: S^T = mfma(K,Q) -> per-lane scalar softmax state,
// O^T = mfma(V^T,P^T) -> in-lane rescale.
// ---------------------------------------------------------------------------
__global__ __launch_bounds__(256) void attn_fwd(
    const u16* __restrict__ Q, const u16* __restrict__ Kb,
    const u16* __restrict__ Vt, u16* __restrict__ Y) {
  const int id = (int)blockIdx.y * (int)gridDim.x + (int)blockIdx.x;
  const int bh = (id & 7) + (((id >> 3) & 3) << 3);
  const int pair = id >> 5;
  const int nqt = (int)(T_SEQ / 64);
  const int tid = threadIdx.x;
  const int wave = tid >> 6, lane = tid & 63;
  const int quad = lane >> 4, l16 = lane & 15;
  const int sw = l16 & 7;  // xor-swizzle key for frag reads
  const u16* Qp = Q + (size_t)bh * T_SEQ * HEAD_D;
  const u16* Kp = Kb + (size_t)bh * T_SEQ * HEAD_D;
  const u16* Vp = Vt + (size_t)bh * HEAD_D * T_SEQ;

  __shared__ u16 Ks[2][64 * 64];
  __shared__ u16 Vs[2][64 * 64];
  __shared__ u16 Pl[4][16 * 72];

  // loop-invariant staging geometry (chunk c -> row c>>3, col8 (c&7)^(row&7))
  const int c1 = tid, c2 = tid + 256;
  const int r1 = c1 >> 3, g1 = ((c1 & 7) ^ (r1 & 7)) * 8;
  const int r2 = c2 >> 3, g2 = ((c2 & 7) ^ (r2 & 7)) * 8;
  const size_t kO1 = (size_t)r1 * HEAD_D + g1, kO2 = (size_t)r2 * HEAD_D + g2;
  const size_t vO1 = (size_t)r1 * T_SEQ + g1, vO2 = (size_t)r2 * T_SEQ + g2;
  u16* const dK1[2] = {&Ks[0][c1 * 8], &Ks[1][c1 * 8]};
  u16* const dK2[2] = {&Ks[0][c2 * 8], &Ks[1][c2 * 8]};
  u16* const dV1[2] = {&Vs[0][c1 * 8], &Vs[1][c1 * 8]};
  u16* const dV2[2] = {&Vs[0][c2 * 8], &Vs[1][c2 * 8]};

  auto stageK = [&](int bb, int k0) {
    const u16* base = Kp + (size_t)k0 * HEAD_D;
    load_lds16(base + kO1, dK1[bb]);
    load_lds16(base + kO2, dK2[bb]);
  };
  auto stageV = [&](int bb, int k0) {
    const u16* base = Vp + k0;
    load_lds16(base + vO1, dV1[bb]);
    load_lds16(base + vO2, dV2[bb]);
  };

  const int b = bh >> 4, h = bh & 15;

#pragma unroll 1
  for (int phase = 0; phase < 2; ++phase) {
    const int qb = phase == 0 ? (nqt - 1 - pair) : pair;
    const int q0 = qb * 64;
    const int qglob = q0 + wave * 16 + l16;  // this lane's q row

    if (phase == 1) __syncthreads();  // protect Ks/Vs from prior readers

    bf16x8 qF[2];
    qF[0] = *(const bf16x8*)&Qp[(size_t)qglob * HEAD_D + quad * 8];
    qF[1] = *(const bf16x8*)&Qp[(size_t)qglob * HEAD_D + 32 + quad * 8];

    f32x4 o[4] = {};   // O^T: d = nt*16 + quad*4 + r, q = l16
    float mrun = -3e38f, lrun = 0.0f;

    stageK(0, 0);
    stageV(0, 0);

    int buf = 0;
    for (int kb = 0; kb <= qb; ++kb) {
      const int k0 = kb * 64;
      __syncthreads();  // drains DMA + all waves' prior-buffer reads
      if (kb < qb) {
        stageK(buf ^ 1, k0 + 64);
        stageV(buf ^ 1, k0 + 64);
      }
      // S^T: key = nt*16 + quad*4 + r (rows), q = l16 (cols)
      f32x4 st[4] = {};
#pragma unroll
      for (int ks = 0; ks < 2; ++ks) {
#pragma unroll
        for (int nt = 0; nt < 4; ++nt) {
          bf16x8 kF = *(const bf16x8*)
              &Ks[buf][(nt * 16 + l16) * 64 + (((ks * 4 + quad) ^ sw) * 8)];
          st[nt] = __builtin_amdgcn_mfma_f32_16x16x32_bf16(kF, qF[ks], st[nt],
                                                           0, 0, 0);
        }
      }
      if (kb == qb) {  // causal mask, diagonal tile only
#pragma unroll
        for (int nt = 0; nt < 4; ++nt) {
#pragma unroll
          for (int r = 0; r < 4; ++r) {
            const int key = k0 + nt * 16 + quad * 4 + r;
            if (key > qglob) st[nt][r] = -3e38f;
          }
        }
      }
      // online softmax over keys: register tree + cross-quad (lanes ^16,^32)
      float m = st[0][0];
#pragma unroll
      for (int nt = 0; nt < 4; ++nt)
#pragma unroll
        for (int r = 0; r < 4; ++r) m = fmaxf(m, st[nt][r]);
      m = fmaxf(m, __shfl_xor(m, 16, 64));
      m = fmaxf(m, __shfl_xor(m, 32, 64));
      const float nm = fmaxf(mrun, m);
      const float alpha = __builtin_amdgcn_exp2f(mrun - nm);
      mrun = nm;
      float sum = 0.0f;
#pragma unroll
      for (int nt = 0; nt < 4; ++nt)
#pragma unroll
        for (int r = 0; r < 4; ++r) {
          const float p = __builtin_amdgcn_exp2f(st[nt][r] - nm);
          st[nt][r] = p;
          sum += p;
        }
      sum += __shfl_xor(sum, 16, 64);
      sum += __shfl_xor(sum, 32, 64);
      lrun = lrun * alpha + sum;
#pragma unroll
      for (int nt = 0; nt < 4; ++nt)
#pragma unroll
        for (int r = 0; r < 4; ++r) o[nt][r] *= alpha;
      // P^T -> LDS: row = q (l16), col = key; v_perm truncating pack
#pragma unroll
      for (int nt = 0; nt < 4; ++nt) {
        uint2 pk;
        pk.x = pk2(st[nt][0], st[nt][1]);
        pk.y = pk2(st[nt][2], st[nt][3]);
        *(uint2*)&Pl[wave][l16 * 72 + nt * 16 + quad * 4] = pk;
      }
      // O^T += V^T P^T  (A = V^T from Vs, B = P^T from Pl)
#pragma unroll
      for (int ks = 0; ks < 2; ++ks) {
        bf16x8 aP = *(const bf16x8*)&Pl[wave][l16 * 72 + ks * 32 + quad * 8];
#pragma unroll
        for (int nt = 0; nt < 4; ++nt) {
          bf16x8 vF = *(const bf16x8*)
              &Vs[buf][(nt * 16 + l16) * 64 + (((ks * 4 + quad) ^ sw) * 8)];
          o[nt] =
              __builtin_amdgcn_mfma_f32_16x16x32_bf16(vF, aP, o[nt], 0, 0, 0);
        }
      }
      buf ^= 1;
    }

    // write O^T / l -> Y bf16 [B,T,C]: row = token (l16), cols = d
    const float rl = 1.0f / lrun;
    u16* yp = Y + ((size_t)(b * T_SEQ + qglob)) * C_EMBD + h * HEAD_D;
#pragma unroll
    for (int nt = 0; nt < 4; ++nt) {
      ushort4 ov;
      ov.x = f2b(o[nt][0] * rl); ov.y = f2b(o[nt][1] * rl);
      ov.z = f2b(o[nt][2] * rl); ov.w = f2b(o[nt][3] * rl);
      *(ushort4*)&yp[nt * 16 + quad * 4] = ov;
    }
  }
}

// ---------------------------------------------------------------------------
// Host side
// ---------------------------------------------------------------------------
extern "C" void kernel_launch(void* const* d_in, const int* in_sizes, int n_in,
                              void* d_out, int out_size, void* d_ws,
                              size_t ws_size, hipStream_t stream) {
  const float* x      = (const float*)d_in[0];
  const float* W_attn = (const float*)d_in[1];
  const float* b_attn = (const float*)d_in[2];
  const float* W_proj = (const float*)d_in[3];
  const float* b_proj = (const float*)d_in[4];
  const float* W_fc   = (const float*)d_in[5];
  const float* b_fc   = (const float*)d_in[6];
  const float* W_fc2  = (const float*)d_in[7];
  const float* b_fc2  = (const float*)d_in[8];
  const float* ln1_g  = (const float*)d_in[9];
  const float* ln1_b  = (const float*)d_in[10];
  const float* ln2_g  = (const float*)d_in[11];
  const float* ln2_b  = (const float*)d_in[12];

  u16* wqkvT = (u16*)d_ws;                            // [3072][1024] bf16
  u16* wprojT = wqkvT + (size_t)3072 * 1024;          // [1024][1024]
  u16* wfcT  = wprojT + (size_t)1024 * 1024;          // [4096][1024]
  u16* wfc2T = wfcT + (size_t)4096 * 1024;            // [1024][4096]
  u16* Abuf  = wfc2T + (size_t)1024 * 4096;           // [4096][1024] bf16
  float* x1  = (float*)(Abuf + (size_t)M_TOK * C_EMBD);  // [4096][1024] f32
  u16* hbuf  = (u16*)(x1 + (size_t)M_TOK * C_EMBD);   // [4096][4096] bf16, 32MB
  float* projP = (float*)hbuf;                        // proj partials 2x16MB (dead window)
  u16* Qb    = hbuf + (size_t)M_TOK * 4096;           // [32][2048][64]
  u16* Kbuf  = Qb + (size_t)32 * T_SEQ * HEAD_D;
  u16* Vtb   = Kbuf + (size_t)32 * T_SEQ * HEAD_D;
  float* fc2P1 = (float*)Qb;                          // fc2 partial z=1 (16MB, dead)

  const dim3 blk(256);

  transpose_cast_all<<<12288, blk, 0, stream>>>(
      W_attn, wqkvT, W_proj, wprojT, W_fc, wfcT, W_fc2, wfc2T);

  ln_cast<<<M_TOK, blk, 0, stream>>>(x, ln1_g, ln1_b, Abuf);

  // qkv GEMM with fused split/reorder/scale epilogue
  gemm_bt<EPI_QKV, 1><<<dim3(3072 / 128, M_TOK / 128), blk, 0, stream>>>(
      Abuf, wqkvT, b_attn, Qb, Kbuf, Vtb, M_TOK, 3072, 1024);

  attn_fwd<<<dim3(T_SEQ / 128, 32), blk, 0, stream>>>(Qb, Kbuf, Vtb, Abuf);

  // proj: split-K=2 partials into hbuf region; reduce fused into ln2
  gemm_bt<EPI_PART, 2><<<dim3(1024 / 128, M_TOK / 128, 2), blk, 0, stream>>>(
      Abuf, wprojT, nullptr, projP, projP + (size_t)M_TOK * C_EMBD, nullptr,
      M_TOK, 1024, 1024);
  ln_reduce_cast<<<M_TOK, blk, 0, stream>>>(
      projP, projP + (size_t)M_TOK * C_EMBD, b_proj, x, ln2_g, ln2_b,
      x1, Abuf);

  gemm_bt<EPI_GELU_BF16, 1><<<dim3(4096 / 128, M_TOK / 128), blk, 0, stream>>>(
      Abuf, wfcT, b_fc, hbuf, nullptr, nullptr, M_TOK, 4096, 1024);

  // fc2: split-K=2, partial z=0 -> d_out, z=1 -> dead Q/K region, reduce in place
  gemm_bt<EPI_PART, 2><<<dim3(1024 / 128, M_TOK / 128, 2), blk, 0, stream>>>(
      hbuf, wfc2T, nullptr, d_out, fc2P1, nullptr, M_TOK, 1024, 4096);
  reduce_add<<<M_TOK * C_EMBD / 1024, blk, 0, stream>>>(
      (const float*)d_out, fc2P1, b_fc2, x1, (float*)d_out);
}